// Round 10
// baseline (6744.547 us; speedup 1.0000x reference)
//
#include <hip/hip_runtime.h>

typedef __attribute__((ext_vector_type(8))) short sv8;   // 8 x bf16 (4 VGPRs)
typedef __attribute__((ext_vector_type(4))) float fv4;   // MFMA accumulator

#define NB 64
#define NT 512
#define NI 1024
#define NH 1024
#define NWG 256
#define NBNH (NB * NH)

__device__ __forceinline__ unsigned short f2bf(float f) {
  union { float f; unsigned u; } v; v.f = f;
  unsigned r = v.u + 0x7fffu + ((v.u >> 16) & 1u);  // round-to-nearest-even
  return (unsigned short)(r >> 16);
}

// bf16 (as ushort) -> f32, header-free
__device__ __forceinline__ float bf2f(unsigned short h) {
  union { unsigned u; float f; } v;
  v.u = ((unsigned)h) << 16;
  return v.f;
}

__device__ __forceinline__ float sigf(float x) {
  return 1.0f / (1.0f + __expf(-x));
}
__device__ __forceinline__ float tanhfast(float x) {
  return 2.0f * sigf(2.0f * x) - 1.0f;
}

// load 8 consecutive f32 -> bf16x8 fragment (in-register)
__device__ __forceinline__ sv8 ldcvt8(const float* p) {
  float4 a = *reinterpret_cast<const float4*>(p);
  float4 b = *reinterpret_cast<const float4*>(p + 4);
  union { sv8 v; unsigned short u[8]; } r;
  r.u[0] = f2bf(a.x); r.u[1] = f2bf(a.y); r.u[2] = f2bf(a.z); r.u[3] = f2bf(a.w);
  r.u[4] = f2bf(b.x); r.u[5] = f2bf(b.y); r.u[6] = f2bf(b.z); r.u[7] = f2bf(b.w);
  return r.v;
}

// MALL-coherent (agent-scope RELAXED -> sc0 sc1, no cache maintenance)
__device__ __forceinline__ unsigned long long ld8_coh(const unsigned short* p) {
  return __hip_atomic_load((const unsigned long long*)p,
                           __ATOMIC_RELAXED, __HIP_MEMORY_SCOPE_AGENT);
}
__device__ __forceinline__ void st2_coh(unsigned short* p, unsigned short v) {
  __hip_atomic_store(p, v, __ATOMIC_RELAXED, __HIP_MEMORY_SCOPE_AGENT);
}
__device__ __forceinline__ unsigned ld4_coh(const unsigned* p) {
  return __hip_atomic_load(p, __ATOMIC_RELAXED, __HIP_MEMORY_SCOPE_AGENT);
}
__device__ __forceinline__ void st4_coh(unsigned* p, unsigned v) {
  __hip_atomic_store(p, v, __ATOMIC_RELAXED, __HIP_MEMORY_SCOPE_AGENT);
}

union hfrag { sv8 v; unsigned long long q[2]; };

__global__ void reset_bar(unsigned* cnt, unsigned* flags) {
  if (threadIdx.x == 0) st4_coh(cnt, 0u);
  if (flags) st4_coh(flags + threadIdx.x * 16, 0u);
}

// linear f32 -> bf16
__global__ void cvt_bf16_lin(const float* __restrict__ in,
                             unsigned short* __restrict__ out, int n4) {
  int i = blockIdx.x * blockDim.x + threadIdx.x;
  if (i >= n4) return;
  float4 v = reinterpret_cast<const float4*>(in)[i];
  ushort4 o;
  o.x = f2bf(v.x); o.y = f2bf(v.y); o.z = f2bf(v.z); o.w = f2bf(v.w);
  reinterpret_cast<ushort4*>(out)[i] = o;
}

// ---- fence-free grid barrier (flag array; counter fallback) ----
__device__ __forceinline__ void bar_arrive(unsigned* cnt, unsigned* flags,
                                           unsigned k) {
  if (flags) {
    if (threadIdx.x == 0) st4_coh(flags + blockIdx.x * 16, k);
  } else {
    if (threadIdx.x == 0)
      __hip_atomic_fetch_add(cnt, 1u, __ATOMIC_RELAXED, __HIP_MEMORY_SCOPE_AGENT);
  }
}
__device__ __forceinline__ void bar_wait(unsigned* cnt, unsigned* flags,
                                         unsigned k) {
  if (flags) {
    if (threadIdx.x < 64) {
      const unsigned* f = flags + threadIdx.x * 16;
      for (;;) {
        bool ok = (ld4_coh(f)            >= k) & (ld4_coh(f + 64 * 16)  >= k) &
                  (ld4_coh(f + 128 * 16) >= k) & (ld4_coh(f + 192 * 16) >= k);
        if (__all(ok)) break;
        __builtin_amdgcn_s_sleep(1);
      }
    }
  } else {
    if (threadIdx.x == 0) {
      const unsigned target = k * NWG;
      while (ld4_coh(cnt) < target) __builtin_amdgcn_s_sleep(4);
    }
  }
  __syncthreads();
}

// ---- one-shot GEMM: xw[s][n] = sum_k x[s][k] * Wi[n][k], bf16 out ----
// grid 16384 WGs x 256 thr; WG = (sg = bid&255, ng = bid>>8) covers
// s in [sg*128, +128), n in [ng*64, +64). Wave wv: 32 s-rows, all 64 n.
// Same fragment conventions as the (validated) lstm kernel.
__global__ void __launch_bounds__(256) gemm_xw(
    const unsigned short* __restrict__ xbf,   // [32768][1024] bf16
    const unsigned short* __restrict__ wibf,  // [4096][1024] bf16
    unsigned short* __restrict__ xw)          // [32768][4096] bf16
{
  const int bid  = blockIdx.x;
  const int sg   = bid & 255;
  const int ng   = bid >> 8;
  const int lane = threadIdx.x & 63;
  const int wv   = threadIdx.x >> 6;
  const int c    = lane & 15;
  const int ko   = (lane >> 4) << 3;
  const int s0   = sg * 128 + wv * 32;
  const int n0   = ng * 64;

  const unsigned short* a0p = xbf + (size_t)(s0 + c) * NI + ko;
  const unsigned short* a1p = xbf + (size_t)(s0 + 16 + c) * NI + ko;
  const unsigned short* b0p = wibf + (size_t)(n0 + c) * NI + ko;

  fv4 acc[2][4];
#pragma unroll
  for (int i = 0; i < 2; ++i)
#pragma unroll
    for (int j = 0; j < 4; ++j) acc[i][j] = fv4{0.f, 0.f, 0.f, 0.f};

#pragma unroll 4
  for (int kk = 0; kk < 32; ++kk) {
    const int kof = kk * 32;
    sv8 a0 = *reinterpret_cast<const sv8*>(a0p + kof);
    sv8 a1 = *reinterpret_cast<const sv8*>(a1p + kof);
#pragma unroll
    for (int j = 0; j < 4; ++j) {
      sv8 b = *reinterpret_cast<const sv8*>(b0p + (size_t)16 * j * NI + kof);
      acc[0][j] = __builtin_amdgcn_mfma_f32_16x16x32_bf16(a0, b, acc[0][j], 0, 0, 0);
      acc[1][j] = __builtin_amdgcn_mfma_f32_16x16x32_bf16(a1, b, acc[1][j], 0, 0, 0);
    }
  }

  // D layout: row = (lane>>4)*4 + r, col = lane&15
#pragma unroll
  for (int i = 0; i < 2; ++i)
#pragma unroll
    for (int j = 0; j < 4; ++j)
#pragma unroll
      for (int r = 0; r < 4; ++r) {
        int row = s0 + 16 * i + ((lane >> 4) << 2) + r;
        int col = n0 + 16 * j + c;
        xw[(size_t)row * 4096 + col] = f2bf(acc[i][j][r]);
      }
}

// ---- hoisted serial loop: preact = xw[s] + h_t @ Wh^T ----
// 256 WGs x 512 thr (8 waves). Wave wv: half = wv>>2 owns k in
// [half*512, +512); wq = wv&3 owns batch rows 16wq..16wq+15.
// Partial sums from the two k-halves are reduced through LDS.
__global__ void __launch_bounds__(512, 1) lstm_hoist(
    const unsigned short* __restrict__ xw,   // [32768][4096] bf16
    const float* __restrict__ Wh,            // [4H][NH] f32
    float* out,                              // f32: hidden, h_T, c_T
    unsigned short* hbuf,                    // 2 * [NB][NH] bf16
    unsigned* cnt, unsigned* flags)
{
  const int w    = blockIdx.x;
  const int tid  = threadIdx.x;
  const int lane = tid & 63;
  const int wv   = tid >> 6;
  const int half = wv >> 2;
  const int wq   = wv & 3;
  const int c    = lane & 15;
  const int ko   = (lane >> 4) << 3;
  const int n    = (c >> 2) * NH + (w << 2) + (c & 3);  // preact column

  __shared__ float pre2[2][64][17];

  // weight fragments for this wave's k-half: 16 x sv8 = 64 VGPR
  sv8 bWh[16];
  {
    const float* wh = Wh + (size_t)n * NH + half * 512 + ko;
#pragma unroll
    for (int kk = 0; kk < 16; ++kk) {
      union { sv8 v; unsigned short u[8]; } ph;
#pragma unroll
      for (int j = 0; j < 8; ++j) ph.u[j] = f2bf(wh[kk * 32 + j]);
      bWh[kk] = ph.v;
    }
  }

  // zero h_0 (buffer 0): 256 WGs x first 256 thr == NB*NH exactly
  if (tid < 256) st2_coh(hbuf + (w << 8) + tid, 0);

  unsigned bar = 1;
  __syncthreads();
  bar_arrive(cnt, flags, bar);
  bar_wait(cnt, flags, bar);

  const int b    = tid >> 2;            // gate threads: tid < 256
  const int d    = tid & 3;
  const int jcol = (w << 2) + d;
  const int arow = (wq << 4) + c;       // batch row for A-fragments

  float cstate = 0.0f, hlast = 0.0f;

  for (int t = 0; t < NT; ++t) {
    // prefetch this thread's 4 xw gate values (hidden under MFMA phase)
    unsigned short xw4[4];
    if (tid < 256) {
      const unsigned short* xwp = xw + ((size_t)b * NT + t) * 4096 + jcol;
#pragma unroll
      for (int g = 0; g < 4; ++g) xw4[g] = xwp[g * 1024];
    }

    const unsigned short* hr =
        hbuf + (t & 1) * NBNH + arow * NH + half * 512 + ko;

    fv4 a0 = {0.f, 0.f, 0.f, 0.f}, a1 = a0;
#pragma unroll
    for (int kk = 0; kk < 16; kk += 2) {
      hfrag h0, h1;
      h0.q[0] = ld8_coh(hr + kk * 32);
      h0.q[1] = ld8_coh(hr + kk * 32 + 4);
      h1.q[0] = ld8_coh(hr + (kk + 1) * 32);
      h1.q[1] = ld8_coh(hr + (kk + 1) * 32 + 4);
      a0 = __builtin_amdgcn_mfma_f32_16x16x32_bf16(h0.v, bWh[kk],     a0, 0, 0, 0);
      a1 = __builtin_amdgcn_mfma_f32_16x16x32_bf16(h1.v, bWh[kk + 1], a1, 0, 0, 0);
    }
    fv4 acc = a0 + a1;

    // D layout: row = (lane>>4)*4 + r, col = lane&15
    {
      int prow = (wq << 4) + ((lane >> 4) << 2);
#pragma unroll
      for (int r = 0; r < 4; ++r) pre2[half][prow + r][c] = acc[r];
    }
    __syncthreads();

    float hv = 0.0f;
    if (tid < 256) {
      float p0 = pre2[0][b][d]      + pre2[1][b][d]      + bf2f(xw4[0]);
      float p1 = pre2[0][b][4 + d]  + pre2[1][b][4 + d]  + bf2f(xw4[1]);
      float p2 = pre2[0][b][8 + d]  + pre2[1][b][8 + d]  + bf2f(xw4[2]);
      float p3 = pre2[0][b][12 + d] + pre2[1][b][12 + d] + bf2f(xw4[3]);
      float it = sigf(sigf(p0));
      float ft = sigf(sigf(p1));
      float ot = sigf(sigf(p2));
      float gt = tanhfast(p3);
      cstate = ft * cstate + it * gt;
      hv = ot * tanhfast(cstate);
      hlast = hv;
      st2_coh(hbuf + ((t & 1) ^ 1) * NBNH + b * NH + jcol, f2bf(hv));
    }
    __syncthreads();                 // drains gate waves' h stores (vmcnt 0)
    ++bar;
    bar_arrive(cnt, flags, bar);
    if (tid < 256) out[(((size_t)b * NT + t) << 10) + jcol] = hv;
    bar_wait(cnt, flags, bar);
  }

  if (tid < 256) {
    out[(size_t)NB * NT * NH + b * NH + jcol]           = hlast;
    out[(size_t)NB * NT * NH + NB * NH + b * NH + jcol] = cstate;
  }
}

// ================= round-8 fallback (unchanged, validated) =================
template <bool XBF>
__global__ void __launch_bounds__(256, 1) lstm_seq(
    const float* __restrict__ xf, const unsigned short* __restrict__ xb,
    const float* __restrict__ Wi, const float* __restrict__ Wh,
    float* out, unsigned short* hbuf, unsigned* cnt, unsigned* flags)
{
  const int w    = blockIdx.x;
  const int tid  = threadIdx.x;
  const int lane = tid & 63;
  const int wv   = tid >> 6;
  const int c    = lane & 15;
  const int ko   = (lane >> 4) << 3;
  const int n    = (c >> 2) * NH + (w << 2) + (c & 3);

  __shared__ float pre[64][17];

  sv8 bWi[32], bWh[32];
  {
    const float* wi = Wi + (size_t)n * NI + ko;
    const float* wh = Wh + (size_t)n * NH + ko;
#pragma unroll
    for (int kk = 0; kk < 32; ++kk) {
      union { sv8 v; unsigned short u[8]; } pi, ph;
#pragma unroll
      for (int j = 0; j < 8; ++j) {
        pi.u[j] = f2bf(wi[kk * 32 + j]);
        ph.u[j] = f2bf(wh[kk * 32 + j]);
      }
      bWi[kk] = pi.v;
      bWh[kk] = ph.v;
    }
  }

  st2_coh(hbuf + (w << 8) + tid, 0);

  unsigned bar = 1;
  __syncthreads();
  bar_arrive(cnt, flags, bar);
  bar_wait(cnt, flags, bar);

  const int b    = tid >> 2;
  const int d    = tid & 3;
  const int jcol = (w << 2) + d;
  const int arow = (wv << 4) + c;

  float cstate = 0.0f, hlast = 0.0f;

  for (int t = 0; t < NT; ++t) {
    const unsigned short* hr = hbuf + (t & 1) * NBNH + arow * NH + ko;
    const unsigned short* xr =
        XBF ? (xb + ((size_t)arow * NT + t) * NI + ko) : nullptr;
    const float* xrf =
        XBF ? nullptr : (xf + ((size_t)arow * NT + t) * NI + ko);

    fv4 a0 = {0.f, 0.f, 0.f, 0.f}, a1 = a0, a2 = a0, a3 = a0;
#pragma unroll
    for (int kk = 0; kk < 32; kk += 2) {
      sv8 ax0, ax1;
      if constexpr (XBF) {
        ax0 = *reinterpret_cast<const sv8*>(xr + kk * 32);
        ax1 = *reinterpret_cast<const sv8*>(xr + (kk + 1) * 32);
      } else {
        ax0 = ldcvt8(xrf + kk * 32);
        ax1 = ldcvt8(xrf + (kk + 1) * 32);
      }
      hfrag h0, h1;
      h0.q[0] = ld8_coh(hr + kk * 32);
      h0.q[1] = ld8_coh(hr + kk * 32 + 4);
      h1.q[0] = ld8_coh(hr + (kk + 1) * 32);
      h1.q[1] = ld8_coh(hr + (kk + 1) * 32 + 4);
      a0 = __builtin_amdgcn_mfma_f32_16x16x32_bf16(ax0,  bWi[kk],     a0, 0, 0, 0);
      a1 = __builtin_amdgcn_mfma_f32_16x16x32_bf16(h0.v, bWh[kk],     a1, 0, 0, 0);
      a2 = __builtin_amdgcn_mfma_f32_16x16x32_bf16(ax1,  bWi[kk + 1], a2, 0, 0, 0);
      a3 = __builtin_amdgcn_mfma_f32_16x16x32_bf16(h1.v, bWh[kk + 1], a3, 0, 0, 0);
    }
    fv4 acc = (a0 + a2) + (a1 + a3);

    {
      int prow = (wv << 4) + ((lane >> 4) << 2);
#pragma unroll
      for (int r = 0; r < 4; ++r) pre[prow + r][c] = acc[r];
    }
    __syncthreads();

    float p0 = pre[b][d];
    float p1 = pre[b][4 + d];
    float p2 = pre[b][8 + d];
    float p3 = pre[b][12 + d];
    float it = sigf(sigf(p0));
    float ft = sigf(sigf(p1));
    float ot = sigf(sigf(p2));
    float gt = tanhfast(p3);
    cstate = ft * cstate + it * gt;
    float hv = ot * tanhfast(cstate);
    hlast = hv;

    st2_coh(hbuf + ((t & 1) ^ 1) * NBNH + b * NH + jcol, f2bf(hv));
    __syncthreads();
    ++bar;
    bar_arrive(cnt, flags, bar);
    out[(((size_t)b * NT + t) << 10) + jcol] = hv;
    bar_wait(cnt, flags, bar);
  }

  out[(size_t)NB * NT * NH + b * NH + jcol]           = hlast;
  out[(size_t)NB * NT * NH + NB * NH + b * NH + jcol] = cstate;
}

extern "C" void kernel_launch(void* const* d_in, const int* in_sizes, int n_in,
                              void* d_out, int out_size, void* d_ws, size_t ws_size,
                              hipStream_t stream) {
  (void)in_sizes; (void)n_in; (void)out_size;
  const float* x  = (const float*)d_in[0];
  const float* Wi = (const float*)d_in[1];
  const float* Wh = (const float*)d_in[2];
  float* out = (float*)d_out;

  // ws layout (every region gated on ws_size before use):
  //   [0,64)       cnt | [64,+16K) flags | [+,+256K) hbuf
  //   [+,+8M) Wi bf16 | [+,+64M) x bf16 | [+,+256M) xw bf16
  const size_t FLAGS_OFF = 64;
  const size_t HBUF_OFF  = FLAGS_OFF + 256 * 64;                    // 16448
  const size_t WIBF_OFF  = HBUF_OFF + (size_t)2 * NBNH * 2;         // 278592
  const size_t XBF_OFF   = WIBF_OFF + (size_t)4096 * 1024 * 2;      // +8 MB
  const size_t XW_OFF    = XBF_OFF + (size_t)NB * NT * NI * 2;      // +64 MB
  const size_t WS_HOIST  = XW_OFF + (size_t)NB * NT * 4096 * 2;     // +256 MB
  const size_t WS_PATHA  = XW_OFF;                                  // round-8 A

  unsigned* cnt = (unsigned*)d_ws;
  unsigned* flags = (ws_size >= HBUF_OFF)
      ? (unsigned*)((char*)d_ws + FLAGS_OFF) : nullptr;
  const bool hbuf_in_ws = ws_size >= WIBF_OFF;

  unsigned short* hbuf = hbuf_in_ws
      ? (unsigned short*)((char*)d_ws + HBUF_OFF)
      : (unsigned short*)(out + (size_t)NB * NT * NH);
  unsigned short* wibf = (unsigned short*)((char*)d_ws + WIBF_OFF);
  unsigned short* xbf  = (unsigned short*)((char*)d_ws + XBF_OFF);
  unsigned short* xw   = (unsigned short*)((char*)d_ws + XW_OFF);

  reset_bar<<<dim3(1), dim3(256), 0, stream>>>(cnt, flags);

  if (ws_size >= WS_HOIST) {
    int n4x = (NB * NT * NI) / 4;
    cvt_bf16_lin<<<dim3(n4x / 256), dim3(256), 0, stream>>>(x, xbf, n4x);
    int n4w = (4096 * 1024) / 4;
    cvt_bf16_lin<<<dim3(n4w / 256), dim3(256), 0, stream>>>(Wi, wibf, n4w);
    gemm_xw<<<dim3(16384), dim3(256), 0, stream>>>(xbf, wibf, xw);
    lstm_hoist<<<dim3(NWG), dim3(512), 0, stream>>>(xw, Wh, out, hbuf, cnt, flags);
  } else if (ws_size >= WS_PATHA) {
    int n4x = (NB * NT * NI) / 4;
    cvt_bf16_lin<<<dim3(n4x / 256), dim3(256), 0, stream>>>(x, xbf, n4x);
    lstm_seq<true><<<dim3(NWG), dim3(256), 0, stream>>>(
        nullptr, xbf, Wi, Wh, out, hbuf, cnt, flags);
  } else {
    lstm_seq<false><<<dim3(NWG), dim3(256), 0, stream>>>(
        x, nullptr, Wi, Wh, out, hbuf, cnt, flags);
  }
}

// Round 11
// 6346.333 us; speedup vs baseline: 1.0627x; 1.0627x over previous
//
#include <hip/hip_runtime.h>

typedef __attribute__((ext_vector_type(8))) short sv8;   // 8 x bf16 (4 VGPRs)
typedef __attribute__((ext_vector_type(4))) float fv4;   // MFMA accumulator

#define NB 64
#define NT 512
#define NI 1024
#define NH 1024
#define NWG 256
#define NBNH (NB * NH)

__device__ __forceinline__ unsigned short f2bf(float f) {
  union { float f; unsigned u; } v; v.f = f;
  unsigned r = v.u + 0x7fffu + ((v.u >> 16) & 1u);  // round-to-nearest-even
  return (unsigned short)(r >> 16);
}

// bf16 (as ushort) -> f32, header-free
__device__ __forceinline__ float bf2f(unsigned short h) {
  union { unsigned u; float f; } v;
  v.u = ((unsigned)h) << 16;
  return v.f;
}

__device__ __forceinline__ float sigf(float x) {
  return 1.0f / (1.0f + __expf(-x));
}
__device__ __forceinline__ float tanhfast(float x) {
  return 2.0f * sigf(2.0f * x) - 1.0f;
}

// load 8 consecutive f32 -> bf16x8 fragment (in-register)
__device__ __forceinline__ sv8 ldcvt8(const float* p) {
  float4 a = *reinterpret_cast<const float4*>(p);
  float4 b = *reinterpret_cast<const float4*>(p + 4);
  union { sv8 v; unsigned short u[8]; } r;
  r.u[0] = f2bf(a.x); r.u[1] = f2bf(a.y); r.u[2] = f2bf(a.z); r.u[3] = f2bf(a.w);
  r.u[4] = f2bf(b.x); r.u[5] = f2bf(b.y); r.u[6] = f2bf(b.z); r.u[7] = f2bf(b.w);
  return r.v;
}

// MALL-coherent (agent-scope RELAXED -> sc0 sc1, no cache maintenance)
__device__ __forceinline__ unsigned long long ld8_coh(const unsigned short* p) {
  return __hip_atomic_load((const unsigned long long*)p,
                           __ATOMIC_RELAXED, __HIP_MEMORY_SCOPE_AGENT);
}
__device__ __forceinline__ void st2_coh(unsigned short* p, unsigned short v) {
  __hip_atomic_store(p, v, __ATOMIC_RELAXED, __HIP_MEMORY_SCOPE_AGENT);
}
__device__ __forceinline__ unsigned ld4_coh(const unsigned* p) {
  return __hip_atomic_load(p, __ATOMIC_RELAXED, __HIP_MEMORY_SCOPE_AGENT);
}
__device__ __forceinline__ void st4_coh(unsigned* p, unsigned v) {
  __hip_atomic_store(p, v, __ATOMIC_RELAXED, __HIP_MEMORY_SCOPE_AGENT);
}

union hfrag { sv8 v; unsigned long long q[2]; };

__global__ void reset_bar(unsigned* cnt, unsigned* flags) {
  if (threadIdx.x == 0) st4_coh(cnt, 0u);
  if (flags) st4_coh(flags + threadIdx.x * 16, 0u);
}

// linear f32 -> bf16
__global__ void cvt_bf16_lin(const float* __restrict__ in,
                             unsigned short* __restrict__ out, int n4) {
  int i = blockIdx.x * blockDim.x + threadIdx.x;
  if (i >= n4) return;
  float4 v = reinterpret_cast<const float4*>(in)[i];
  ushort4 o;
  o.x = f2bf(v.x); o.y = f2bf(v.y); o.z = f2bf(v.z); o.w = f2bf(v.w);
  reinterpret_cast<ushort4*>(out)[i] = o;
}

// ---- fence-free grid barrier (flag array; counter fallback) ----
__device__ __forceinline__ void bar_arrive(unsigned* cnt, unsigned* flags,
                                           unsigned k) {
  if (flags) {
    if (threadIdx.x == 0) st4_coh(flags + blockIdx.x * 16, k);
  } else {
    if (threadIdx.x == 0)
      __hip_atomic_fetch_add(cnt, 1u, __ATOMIC_RELAXED, __HIP_MEMORY_SCOPE_AGENT);
  }
}
__device__ __forceinline__ void bar_wait(unsigned* cnt, unsigned* flags,
                                         unsigned k) {
  if (flags) {
    if (threadIdx.x < 64) {
      const unsigned* f = flags + threadIdx.x * 16;
      for (;;) {
        bool ok = (ld4_coh(f)            >= k) & (ld4_coh(f + 64 * 16)  >= k) &
                  (ld4_coh(f + 128 * 16) >= k) & (ld4_coh(f + 192 * 16) >= k);
        if (__all(ok)) break;
        __builtin_amdgcn_s_sleep(1);
      }
    }
  } else {
    if (threadIdx.x == 0) {
      const unsigned target = k * NWG;
      while (ld4_coh(cnt) < target) __builtin_amdgcn_s_sleep(4);
    }
  }
  __syncthreads();
}

// ---- one-shot GEMM: xw[s][n] = sum_k x[s][k] * Wi[n][k], bf16 out ----
__global__ void __launch_bounds__(256) gemm_xw(
    const unsigned short* __restrict__ xbf,   // [32768][1024] bf16
    const unsigned short* __restrict__ wibf,  // [4096][1024] bf16
    unsigned short* __restrict__ xw)          // [32768][4096] bf16
{
  const int bid  = blockIdx.x;
  const int sg   = bid & 255;
  const int ng   = bid >> 8;
  const int lane = threadIdx.x & 63;
  const int wv   = threadIdx.x >> 6;
  const int c    = lane & 15;
  const int ko   = (lane >> 4) << 3;
  const int s0   = sg * 128 + wv * 32;
  const int n0   = ng * 64;

  const unsigned short* a0p = xbf + (size_t)(s0 + c) * NI + ko;
  const unsigned short* a1p = xbf + (size_t)(s0 + 16 + c) * NI + ko;
  const unsigned short* b0p = wibf + (size_t)(n0 + c) * NI + ko;

  fv4 acc[2][4];
#pragma unroll
  for (int i = 0; i < 2; ++i)
#pragma unroll
    for (int j = 0; j < 4; ++j) acc[i][j] = fv4{0.f, 0.f, 0.f, 0.f};

#pragma unroll 4
  for (int kk = 0; kk < 32; ++kk) {
    const int kof = kk * 32;
    sv8 a0 = *reinterpret_cast<const sv8*>(a0p + kof);
    sv8 a1 = *reinterpret_cast<const sv8*>(a1p + kof);
#pragma unroll
    for (int j = 0; j < 4; ++j) {
      sv8 b = *reinterpret_cast<const sv8*>(b0p + (size_t)16 * j * NI + kof);
      acc[0][j] = __builtin_amdgcn_mfma_f32_16x16x32_bf16(a0, b, acc[0][j], 0, 0, 0);
      acc[1][j] = __builtin_amdgcn_mfma_f32_16x16x32_bf16(a1, b, acc[1][j], 0, 0, 0);
    }
  }

#pragma unroll
  for (int i = 0; i < 2; ++i)
#pragma unroll
    for (int j = 0; j < 4; ++j)
#pragma unroll
      for (int r = 0; r < 4; ++r) {
        int row = s0 + 16 * i + ((lane >> 4) << 2) + r;
        int col = n0 + 16 * j + c;
        xw[(size_t)row * 4096 + col] = f2bf(acc[i][j][r]);
      }
}

// ---- hoisted serial loop: preact = xw[s] + h_t @ Wh^T ----
// 256 WGs x 512 thr (8 waves). Wave wv: half = wv>>2 owns k-half;
// wq = wv&3 owns batch rows 16wq..16wq+15. LDS reduce over 2 halves.
// ROUND-11 CHANGE: all 32 coherent h-loads issue as one contiguous block
// (atomic loads are never reordered by the compiler -- interleaving them
// with MFMAs serialized 8 MALL round-trips; the block form pays ~1).
__global__ void __launch_bounds__(512, 1) lstm_hoist(
    const unsigned short* __restrict__ xw,   // [32768][4096] bf16
    const float* __restrict__ Wh,            // [4H][NH] f32
    float* out,                              // f32: hidden, h_T, c_T
    unsigned short* hbuf,                    // 2 * [NB][NH] bf16
    unsigned* cnt, unsigned* flags)
{
  const int w    = blockIdx.x;
  const int tid  = threadIdx.x;
  const int lane = tid & 63;
  const int wv   = tid >> 6;
  const int half = wv >> 2;
  const int wq   = wv & 3;
  const int c    = lane & 15;
  const int ko   = (lane >> 4) << 3;
  const int n    = (c >> 2) * NH + (w << 2) + (c & 3);  // preact column

  __shared__ float pre2[2][64][17];

  // weight fragments for this wave's k-half: 16 x sv8 = 64 VGPR
  sv8 bWh[16];
  {
    const float* wh = Wh + (size_t)n * NH + half * 512 + ko;
#pragma unroll
    for (int kk = 0; kk < 16; ++kk) {
      union { sv8 v; unsigned short u[8]; } ph;
#pragma unroll
      for (int j = 0; j < 8; ++j) ph.u[j] = f2bf(wh[kk * 32 + j]);
      bWh[kk] = ph.v;
    }
  }

  // zero h_0 (buffer 0): 256 WGs x first 256 thr == NB*NH exactly
  if (tid < 256) st2_coh(hbuf + (w << 8) + tid, 0);

  unsigned bar = 1;
  __syncthreads();
  bar_arrive(cnt, flags, bar);
  bar_wait(cnt, flags, bar);

  const int b    = tid >> 2;            // gate threads: tid < 256
  const int d    = tid & 3;
  const int jcol = (w << 2) + d;
  const int arow = (wq << 4) + c;       // batch row for A-fragments

  float cstate = 0.0f, hlast = 0.0f;

  // initial xw prefetch (t = 0); subsequent prefetches at loop bottom
  unsigned short xwc[4] = {0, 0, 0, 0};
  if (tid < 256) {
    const unsigned short* xwp = xw + ((size_t)b * NT + 0) * 4096 + jcol;
#pragma unroll
    for (int g = 0; g < 4; ++g) xwc[g] = xwp[g * 1024];
  }

  for (int t = 0; t < NT; ++t) {
    const unsigned short* hr =
        hbuf + (t & 1) * NBNH + arow * NH + half * 512 + ko;

    // ---- hoisted h-load block: 32 coherent 8B loads, back-to-back ----
    hfrag hh[16];
#pragma unroll
    for (int kk = 0; kk < 16; ++kk) {
      hh[kk].q[0] = ld8_coh(hr + kk * 32);
      hh[kk].q[1] = ld8_coh(hr + kk * 32 + 4);
    }

    // ---- MFMA block (first s_waitcnt lands here, ~1 MALL round-trip) ----
    fv4 a0 = {0.f, 0.f, 0.f, 0.f}, a1 = a0;
#pragma unroll
    for (int kk = 0; kk < 16; kk += 2) {
      a0 = __builtin_amdgcn_mfma_f32_16x16x32_bf16(hh[kk].v,     bWh[kk],     a0, 0, 0, 0);
      a1 = __builtin_amdgcn_mfma_f32_16x16x32_bf16(hh[kk + 1].v, bWh[kk + 1], a1, 0, 0, 0);
    }
    fv4 acc = a0 + a1;

    // D layout: row = (lane>>4)*4 + r, col = lane&15
    {
      int prow = (wq << 4) + ((lane >> 4) << 2);
#pragma unroll
      for (int r = 0; r < 4; ++r) pre2[half][prow + r][c] = acc[r];
    }
    __syncthreads();

    float hv = 0.0f;
    if (tid < 256) {
      float p0 = pre2[0][b][d]      + pre2[1][b][d]      + bf2f(xwc[0]);
      float p1 = pre2[0][b][4 + d]  + pre2[1][b][4 + d]  + bf2f(xwc[1]);
      float p2 = pre2[0][b][8 + d]  + pre2[1][b][8 + d]  + bf2f(xwc[2]);
      float p3 = pre2[0][b][12 + d] + pre2[1][b][12 + d] + bf2f(xwc[3]);
      float it = sigf(sigf(p0));
      float ft = sigf(sigf(p1));
      float ot = sigf(sigf(p2));
      float gt = tanhfast(p3);
      cstate = ft * cstate + it * gt;
      hv = ot * tanhfast(cstate);
      hlast = hv;
      st2_coh(hbuf + ((t & 1) ^ 1) * NBNH + b * NH + jcol, f2bf(hv));
    }
    __syncthreads();                 // drains gate waves' h stores (vmcnt 0)
    ++bar;
    bar_arrive(cnt, flags, bar);
    // latency of these two sits under the barrier spin:
    if (tid < 256) {
      out[(((size_t)b * NT + t) << 10) + jcol] = hv;
      if (t + 1 < NT) {
        const unsigned short* xwp = xw + ((size_t)b * NT + t + 1) * 4096 + jcol;
#pragma unroll
        for (int g = 0; g < 4; ++g) xwc[g] = xwp[g * 1024];
      }
    }
    bar_wait(cnt, flags, bar);
  }

  if (tid < 256) {
    out[(size_t)NB * NT * NH + b * NH + jcol]           = hlast;
    out[(size_t)NB * NT * NH + NB * NH + b * NH + jcol] = cstate;
  }
}

// ================= round-8 fallback (unchanged, validated) =================
template <bool XBF>
__global__ void __launch_bounds__(256, 1) lstm_seq(
    const float* __restrict__ xf, const unsigned short* __restrict__ xb,
    const float* __restrict__ Wi, const float* __restrict__ Wh,
    float* out, unsigned short* hbuf, unsigned* cnt, unsigned* flags)
{
  const int w    = blockIdx.x;
  const int tid  = threadIdx.x;
  const int lane = tid & 63;
  const int wv   = tid >> 6;
  const int c    = lane & 15;
  const int ko   = (lane >> 4) << 3;
  const int n    = (c >> 2) * NH + (w << 2) + (c & 3);

  __shared__ float pre[64][17];

  sv8 bWi[32], bWh[32];
  {
    const float* wi = Wi + (size_t)n * NI + ko;
    const float* wh = Wh + (size_t)n * NH + ko;
#pragma unroll
    for (int kk = 0; kk < 32; ++kk) {
      union { sv8 v; unsigned short u[8]; } pi, ph;
#pragma unroll
      for (int j = 0; j < 8; ++j) {
        pi.u[j] = f2bf(wi[kk * 32 + j]);
        ph.u[j] = f2bf(wh[kk * 32 + j]);
      }
      bWi[kk] = pi.v;
      bWh[kk] = ph.v;
    }
  }

  st2_coh(hbuf + (w << 8) + tid, 0);

  unsigned bar = 1;
  __syncthreads();
  bar_arrive(cnt, flags, bar);
  bar_wait(cnt, flags, bar);

  const int b    = tid >> 2;
  const int d    = tid & 3;
  const int jcol = (w << 2) + d;
  const int arow = (wv << 4) + c;

  float cstate = 0.0f, hlast = 0.0f;

  for (int t = 0; t < NT; ++t) {
    const unsigned short* hr = hbuf + (t & 1) * NBNH + arow * NH + ko;
    const unsigned short* xr =
        XBF ? (xb + ((size_t)arow * NT + t) * NI + ko) : nullptr;
    const float* xrf =
        XBF ? nullptr : (xf + ((size_t)arow * NT + t) * NI + ko);

    fv4 a0 = {0.f, 0.f, 0.f, 0.f}, a1 = a0, a2 = a0, a3 = a0;
#pragma unroll
    for (int kk = 0; kk < 32; kk += 2) {
      sv8 ax0, ax1;
      if constexpr (XBF) {
        ax0 = *reinterpret_cast<const sv8*>(xr + kk * 32);
        ax1 = *reinterpret_cast<const sv8*>(xr + (kk + 1) * 32);
      } else {
        ax0 = ldcvt8(xrf + kk * 32);
        ax1 = ldcvt8(xrf + (kk + 1) * 32);
      }
      hfrag h0, h1;
      h0.q[0] = ld8_coh(hr + kk * 32);
      h0.q[1] = ld8_coh(hr + kk * 32 + 4);
      h1.q[0] = ld8_coh(hr + (kk + 1) * 32);
      h1.q[1] = ld8_coh(hr + (kk + 1) * 32 + 4);
      a0 = __builtin_amdgcn_mfma_f32_16x16x32_bf16(ax0,  bWi[kk],     a0, 0, 0, 0);
      a1 = __builtin_amdgcn_mfma_f32_16x16x32_bf16(h0.v, bWh[kk],     a1, 0, 0, 0);
      a2 = __builtin_amdgcn_mfma_f32_16x16x32_bf16(ax1,  bWi[kk + 1], a2, 0, 0, 0);
      a3 = __builtin_amdgcn_mfma_f32_16x16x32_bf16(h1.v, bWh[kk + 1], a3, 0, 0, 0);
    }
    fv4 acc = (a0 + a2) + (a1 + a3);

    {
      int prow = (wv << 4) + ((lane >> 4) << 2);
#pragma unroll
      for (int r = 0; r < 4; ++r) pre[prow + r][c] = acc[r];
    }
    __syncthreads();

    float p0 = pre[b][d];
    float p1 = pre[b][4 + d];
    float p2 = pre[b][8 + d];
    float p3 = pre[b][12 + d];
    float it = sigf(sigf(p0));
    float ft = sigf(sigf(p1));
    float ot = sigf(sigf(p2));
    float gt = tanhfast(p3);
    cstate = ft * cstate + it * gt;
    float hv = ot * tanhfast(cstate);
    hlast = hv;

    st2_coh(hbuf + ((t & 1) ^ 1) * NBNH + b * NH + jcol, f2bf(hv));
    __syncthreads();
    ++bar;
    bar_arrive(cnt, flags, bar);
    out[(((size_t)b * NT + t) << 10) + jcol] = hv;
    bar_wait(cnt, flags, bar);
  }

  out[(size_t)NB * NT * NH + b * NH + jcol]           = hlast;
  out[(size_t)NB * NT * NH + NB * NH + b * NH + jcol] = cstate;
}

extern "C" void kernel_launch(void* const* d_in, const int* in_sizes, int n_in,
                              void* d_out, int out_size, void* d_ws, size_t ws_size,
                              hipStream_t stream) {
  (void)in_sizes; (void)n_in; (void)out_size;
  const float* x  = (const float*)d_in[0];
  const float* Wi = (const float*)d_in[1];
  const float* Wh = (const float*)d_in[2];
  float* out = (float*)d_out;

  // ws layout (every region gated on ws_size before use):
  //   [0,64)       cnt | [64,+16K) flags | [+,+256K) hbuf
  //   [+,+8M) Wi bf16 | [+,+64M) x bf16 | [+,+256M) xw bf16
  const size_t FLAGS_OFF = 64;
  const size_t HBUF_OFF  = FLAGS_OFF + 256 * 64;                    // 16448
  const size_t WIBF_OFF  = HBUF_OFF + (size_t)2 * NBNH * 2;         // 278592
  const size_t XBF_OFF   = WIBF_OFF + (size_t)4096 * 1024 * 2;      // +8 MB
  const size_t XW_OFF    = XBF_OFF + (size_t)NB * NT * NI * 2;      // +64 MB
  const size_t WS_HOIST  = XW_OFF + (size_t)NB * NT * 4096 * 2;     // +256 MB
  const size_t WS_PATHA  = XW_OFF;                                  // round-8 A

  unsigned* cnt = (unsigned*)d_ws;
  unsigned* flags = (ws_size >= HBUF_OFF)
      ? (unsigned*)((char*)d_ws + FLAGS_OFF) : nullptr;
  const bool hbuf_in_ws = ws_size >= WIBF_OFF;

  unsigned short* hbuf = hbuf_in_ws
      ? (unsigned short*)((char*)d_ws + HBUF_OFF)
      : (unsigned short*)(out + (size_t)NB * NT * NH);
  unsigned short* wibf = (unsigned short*)((char*)d_ws + WIBF_OFF);
  unsigned short* xbf  = (unsigned short*)((char*)d_ws + XBF_OFF);
  unsigned short* xw   = (unsigned short*)((char*)d_ws + XW_OFF);

  reset_bar<<<dim3(1), dim3(256), 0, stream>>>(cnt, flags);

  if (ws_size >= WS_HOIST) {
    int n4x = (NB * NT * NI) / 4;
    cvt_bf16_lin<<<dim3(n4x / 256), dim3(256), 0, stream>>>(x, xbf, n4x);
    int n4w = (4096 * 1024) / 4;
    cvt_bf16_lin<<<dim3(n4w / 256), dim3(256), 0, stream>>>(Wi, wibf, n4w);
    gemm_xw<<<dim3(16384), dim3(256), 0, stream>>>(xbf, wibf, xw);
    lstm_hoist<<<dim3(NWG), dim3(512), 0, stream>>>(xw, Wh, out, hbuf, cnt, flags);
  } else if (ws_size >= WS_PATHA) {
    int n4x = (NB * NT * NI) / 4;
    cvt_bf16_lin<<<dim3(n4x / 256), dim3(256), 0, stream>>>(x, xbf, n4x);
    lstm_seq<true><<<dim3(NWG), dim3(256), 0, stream>>>(
        nullptr, xbf, Wi, Wh, out, hbuf, cnt, flags);
  } else {
    lstm_seq<false><<<dim3(NWG), dim3(256), 0, stream>>>(
        x, nullptr, Wi, Wh, out, hbuf, cnt, flags);
  }
}

// Round 12
// 4817.019 us; speedup vs baseline: 1.4001x; 1.3175x over previous
//
#include <hip/hip_runtime.h>

typedef __attribute__((ext_vector_type(8))) short sv8;       // 8 x bf16
typedef __attribute__((ext_vector_type(4))) float fv4;       // MFMA acc
typedef __attribute__((ext_vector_type(4))) unsigned int uv4;// 16B payload

#define NB 64
#define NT 512
#define NI 1024
#define NH 1024
#define NWG 256
#define NBNH (NB * NH)

__device__ __forceinline__ unsigned short f2bf(float f) {
  union { float f; unsigned u; } v; v.f = f;
  unsigned r = v.u + 0x7fffu + ((v.u >> 16) & 1u);  // RNE
  return (unsigned short)(r >> 16);
}
__device__ __forceinline__ float bf2f(unsigned short h) {
  union { unsigned u; float f; } v;
  v.u = ((unsigned)h) << 16;
  return v.f;
}
__device__ __forceinline__ float sigf(float x) {
  return 1.0f / (1.0f + __expf(-x));
}
__device__ __forceinline__ float tanhfast(float x) {
  return 2.0f * sigf(2.0f * x) - 1.0f;
}
__device__ __forceinline__ sv8 ldcvt8(const float* p) {
  float4 a = *reinterpret_cast<const float4*>(p);
  float4 b = *reinterpret_cast<const float4*>(p + 4);
  union { sv8 v; unsigned short u[8]; } r;
  r.u[0] = f2bf(a.x); r.u[1] = f2bf(a.y); r.u[2] = f2bf(a.z); r.u[3] = f2bf(a.w);
  r.u[4] = f2bf(b.x); r.u[5] = f2bf(b.y); r.u[6] = f2bf(b.z); r.u[7] = f2bf(b.w);
  return r.v;
}

// MALL-coherent accessors (agent-scope RELAXED -> sc0 sc1, no cache maint.)
__device__ __forceinline__ unsigned long long ld8_coh(const unsigned short* p) {
  return __hip_atomic_load((const unsigned long long*)p,
                           __ATOMIC_RELAXED, __HIP_MEMORY_SCOPE_AGENT);
}
__device__ __forceinline__ void st2_coh(unsigned short* p, unsigned short v) {
  __hip_atomic_store(p, v, __ATOMIC_RELAXED, __HIP_MEMORY_SCOPE_AGENT);
}
__device__ __forceinline__ void st8_coh(unsigned long long* p, unsigned long long v) {
  __hip_atomic_store(p, v, __ATOMIC_RELAXED, __HIP_MEMORY_SCOPE_AGENT);
}
__device__ __forceinline__ unsigned ld4_coh(const unsigned* p) {
  return __hip_atomic_load(p, __ATOMIC_RELAXED, __HIP_MEMORY_SCOPE_AGENT);
}
__device__ __forceinline__ void st4_coh(unsigned* p, unsigned v) {
  __hip_atomic_store(p, v, __ATOMIC_RELAXED, __HIP_MEMORY_SCOPE_AGENT);
}

union hfrag { sv8 v; unsigned long long q[2]; };

// 16 x 16B coherent loads (64B apart), single waitcnt, one asm block.
// Data-dependence on the outputs orders consumers after the waitcnt.
__device__ __forceinline__ void ld_h_block(const unsigned short* hr, uv4 hh[16]) {
  asm volatile(
      "global_load_dwordx4 %0, %16, off sc0 sc1\n\t"
      "global_load_dwordx4 %1, %16, off offset:64 sc0 sc1\n\t"
      "global_load_dwordx4 %2, %16, off offset:128 sc0 sc1\n\t"
      "global_load_dwordx4 %3, %16, off offset:192 sc0 sc1\n\t"
      "global_load_dwordx4 %4, %16, off offset:256 sc0 sc1\n\t"
      "global_load_dwordx4 %5, %16, off offset:320 sc0 sc1\n\t"
      "global_load_dwordx4 %6, %16, off offset:384 sc0 sc1\n\t"
      "global_load_dwordx4 %7, %16, off offset:448 sc0 sc1\n\t"
      "global_load_dwordx4 %8, %16, off offset:512 sc0 sc1\n\t"
      "global_load_dwordx4 %9, %16, off offset:576 sc0 sc1\n\t"
      "global_load_dwordx4 %10, %16, off offset:640 sc0 sc1\n\t"
      "global_load_dwordx4 %11, %16, off offset:704 sc0 sc1\n\t"
      "global_load_dwordx4 %12, %16, off offset:768 sc0 sc1\n\t"
      "global_load_dwordx4 %13, %16, off offset:832 sc0 sc1\n\t"
      "global_load_dwordx4 %14, %16, off offset:896 sc0 sc1\n\t"
      "global_load_dwordx4 %15, %16, off offset:960 sc0 sc1\n\t"
      "s_waitcnt vmcnt(0)"
      : "=&v"(hh[0]), "=&v"(hh[1]), "=&v"(hh[2]), "=&v"(hh[3]),
        "=&v"(hh[4]), "=&v"(hh[5]), "=&v"(hh[6]), "=&v"(hh[7]),
        "=&v"(hh[8]), "=&v"(hh[9]), "=&v"(hh[10]), "=&v"(hh[11]),
        "=&v"(hh[12]), "=&v"(hh[13]), "=&v"(hh[14]), "=&v"(hh[15])
      : "v"(hr)
      : "memory");
}

__global__ void reset_bar(unsigned* cnt, unsigned* flags, unsigned* epoch) {
  if (threadIdx.x == 0) { st4_coh(cnt, 0u); if (epoch) st4_coh(epoch, 0u); }
  if (flags) st4_coh(flags + threadIdx.x * 16, 0u);
}

__global__ void cvt_bf16_lin(const float* __restrict__ in,
                             unsigned short* __restrict__ out, int n4) {
  int i = blockIdx.x * blockDim.x + threadIdx.x;
  if (i >= n4) return;
  float4 v = reinterpret_cast<const float4*>(in)[i];
  ushort4 o;
  o.x = f2bf(v.x); o.y = f2bf(v.y); o.z = f2bf(v.z); o.w = f2bf(v.w);
  reinterpret_cast<ushort4*>(out)[i] = o;
}

// ---- two-level fence-free grid barrier ----
// arrive: WG stores its own flag (no RMW). wait: WG 0's wave 0 is the sole
// aggregator -- polls all 256 flags, publishes a single epoch word; all other
// WGs poll epoch with ONE lane + ONE load. Kills the 256-WG x 64-lane poll
// storm on MALL (round 11 evidence: request congestion, not latency chain).
__device__ __forceinline__ void bar_arrive(unsigned* cnt, unsigned* flags,
                                           unsigned k) {
  if (flags) {
    if (threadIdx.x == 0) st4_coh(flags + blockIdx.x * 16, k);
  } else {
    if (threadIdx.x == 0)
      __hip_atomic_fetch_add(cnt, 1u, __ATOMIC_RELAXED, __HIP_MEMORY_SCOPE_AGENT);
  }
}
__device__ __forceinline__ void bar_wait(unsigned* cnt, unsigned* flags,
                                         unsigned* epoch, unsigned k) {
  if (flags) {
    if (blockIdx.x == 0) {
      if (threadIdx.x < 64) {
        const unsigned* f = flags + threadIdx.x * 16;
        for (;;) {
          bool ok = (ld4_coh(f)            >= k) & (ld4_coh(f + 64 * 16)  >= k) &
                    (ld4_coh(f + 128 * 16) >= k) & (ld4_coh(f + 192 * 16) >= k);
          if (__all(ok)) break;
          __builtin_amdgcn_s_sleep(1);
        }
        if (threadIdx.x == 0) st4_coh(epoch, k);
      }
    } else {
      if (threadIdx.x == 0) {
        while (ld4_coh(epoch) < k) __builtin_amdgcn_s_sleep(2);
      }
    }
  } else {
    if (threadIdx.x == 0) {
      const unsigned target = k * NWG;
      while (ld4_coh(cnt) < target) __builtin_amdgcn_s_sleep(4);
    }
  }
  __syncthreads();
}

// ---- one-shot GEMM: xw[s][n] = sum_k x[s][k] * Wi[n][k] (unchanged) ----
__global__ void __launch_bounds__(256) gemm_xw(
    const unsigned short* __restrict__ xbf,
    const unsigned short* __restrict__ wibf,
    unsigned short* __restrict__ xw)
{
  const int bid  = blockIdx.x;
  const int sg   = bid & 255;
  const int ng   = bid >> 8;
  const int lane = threadIdx.x & 63;
  const int wv   = threadIdx.x >> 6;
  const int c    = lane & 15;
  const int ko   = (lane >> 4) << 3;
  const int s0   = sg * 128 + wv * 32;
  const int n0   = ng * 64;

  const unsigned short* a0p = xbf + (size_t)(s0 + c) * NI + ko;
  const unsigned short* a1p = xbf + (size_t)(s0 + 16 + c) * NI + ko;
  const unsigned short* b0p = wibf + (size_t)(n0 + c) * NI + ko;

  fv4 acc[2][4];
#pragma unroll
  for (int i = 0; i < 2; ++i)
#pragma unroll
    for (int j = 0; j < 4; ++j) acc[i][j] = fv4{0.f, 0.f, 0.f, 0.f};

#pragma unroll 4
  for (int kk = 0; kk < 32; ++kk) {
    const int kof = kk * 32;
    sv8 a0 = *reinterpret_cast<const sv8*>(a0p + kof);
    sv8 a1 = *reinterpret_cast<const sv8*>(a1p + kof);
#pragma unroll
    for (int j = 0; j < 4; ++j) {
      sv8 b = *reinterpret_cast<const sv8*>(b0p + (size_t)16 * j * NI + kof);
      acc[0][j] = __builtin_amdgcn_mfma_f32_16x16x32_bf16(a0, b, acc[0][j], 0, 0, 0);
      acc[1][j] = __builtin_amdgcn_mfma_f32_16x16x32_bf16(a1, b, acc[1][j], 0, 0, 0);
    }
  }

#pragma unroll
  for (int i = 0; i < 2; ++i)
#pragma unroll
    for (int j = 0; j < 4; ++j)
#pragma unroll
      for (int r = 0; r < 4; ++r) {
        int row = s0 + 16 * i + ((lane >> 4) << 2) + r;
        int col = n0 + 16 * j + c;
        xw[(size_t)row * 4096 + col] = f2bf(acc[i][j][r]);
      }
}

// ---- hoisted serial loop: preact = xw[s] + h_t @ Wh^T ----
__global__ void __launch_bounds__(512, 1) lstm_hoist(
    const unsigned short* __restrict__ xw,
    const float* __restrict__ Wh,
    float* out,
    unsigned short* hbuf,
    unsigned* cnt, unsigned* flags, unsigned* epoch)
{
  const int w    = blockIdx.x;
  const int tid  = threadIdx.x;
  const int lane = tid & 63;
  const int wv   = tid >> 6;
  const int half = wv >> 2;
  const int wq   = wv & 3;
  const int c    = lane & 15;
  const int ko   = (lane >> 4) << 3;
  const int n    = (c >> 2) * NH + (w << 2) + (c & 3);

  __shared__ float pre2[2][64][17];

  sv8 bWh[16];
  {
    const float* wh = Wh + (size_t)n * NH + half * 512 + ko;
#pragma unroll
    for (int kk = 0; kk < 16; ++kk) {
      union { sv8 v; unsigned short u[8]; } ph;
#pragma unroll
      for (int j = 0; j < 8; ++j) ph.u[j] = f2bf(wh[kk * 32 + j]);
      bWh[kk] = ph.v;
    }
  }

  if (tid < 256) st2_coh(hbuf + (w << 8) + tid, 0);

  unsigned bar = 1;
  __syncthreads();
  bar_arrive(cnt, flags, bar);
  bar_wait(cnt, flags, epoch, bar);

  const int b    = tid >> 2;        // gate threads: tid < 256
  const int d    = tid & 3;
  const int jcol = (w << 2) + d;
  const int arow = (wq << 4) + c;

  float cstate = 0.0f, hlast = 0.0f;

  unsigned short xwc[4] = {0, 0, 0, 0};
  if (tid < 256) {
    const unsigned short* xwp = xw + ((size_t)b * NT + 0) * 4096 + jcol;
#pragma unroll
    for (int g = 0; g < 4; ++g) xwc[g] = xwp[g * 1024];
  }

  for (int t = 0; t < NT; ++t) {
    const unsigned short* hr =
        hbuf + (t & 1) * NBNH + arow * NH + half * 512 + ko;

    // 16 x 16B coherent loads, one waitcnt (request-count halved vs 8B)
    uv4 hh[16];
    ld_h_block(hr, hh);

    fv4 a0 = {0.f, 0.f, 0.f, 0.f}, a1 = a0;
#pragma unroll
    for (int kk = 0; kk < 16; kk += 2) {
      union { uv4 u; sv8 s; } c0, c1;
      c0.u = hh[kk];
      c1.u = hh[kk + 1];
      a0 = __builtin_amdgcn_mfma_f32_16x16x32_bf16(c0.s, bWh[kk],     a0, 0, 0, 0);
      a1 = __builtin_amdgcn_mfma_f32_16x16x32_bf16(c1.s, bWh[kk + 1], a1, 0, 0, 0);
    }
    fv4 acc = a0 + a1;

    // D layout: row = (lane>>4)*4 + r, col = lane&15
    {
      int prow = (wq << 4) + ((lane >> 4) << 2);
#pragma unroll
      for (int r = 0; r < 4; ++r) pre2[half][prow + r][c] = acc[r];
    }
    __syncthreads();

    float hv = 0.0f;
    if (tid < 256) {
      float p0 = pre2[0][b][d]      + pre2[1][b][d]      + bf2f(xwc[0]);
      float p1 = pre2[0][b][4 + d]  + pre2[1][b][4 + d]  + bf2f(xwc[1]);
      float p2 = pre2[0][b][8 + d]  + pre2[1][b][8 + d]  + bf2f(xwc[2]);
      float p3 = pre2[0][b][12 + d] + pre2[1][b][12 + d] + bf2f(xwc[3]);
      float it = sigf(sigf(p0));
      float ft = sigf(sigf(p1));
      float ot = sigf(sigf(p2));
      float gt = tanhfast(p3);
      cstate = ft * cstate + it * gt;
      hv = ot * tanhfast(cstate);
      hlast = hv;
      // pack 4 neighbors' bf16 h into one 8B coherent store (4x fewer reqs)
      int hbi = (int)f2bf(hv);
      int h1 = __shfl_down(hbi, 1);
      int h2 = __shfl_down(hbi, 2);
      int h3 = __shfl_down(hbi, 3);
      if (d == 0) {
        unsigned long long pk =
            (unsigned long long)(unsigned short)hbi |
            ((unsigned long long)(unsigned short)h1 << 16) |
            ((unsigned long long)(unsigned short)h2 << 32) |
            ((unsigned long long)(unsigned short)h3 << 48);
        st8_coh((unsigned long long*)(hbuf + ((t & 1) ^ 1) * NBNH +
                                      b * NH + (w << 2)), pk);
      }
    }
    __syncthreads();                 // drains h stores (vmcnt 0)
    ++bar;
    bar_arrive(cnt, flags, bar);
    if (tid < 256) {
      out[(((size_t)b * NT + t) << 10) + jcol] = hv;
      if (t + 1 < NT) {
        const unsigned short* xwp = xw + ((size_t)b * NT + t + 1) * 4096 + jcol;
#pragma unroll
        for (int g = 0; g < 4; ++g) xwc[g] = xwp[g * 1024];
      }
    }
    bar_wait(cnt, flags, epoch, bar);
  }

  if (tid < 256) {
    out[(size_t)NB * NT * NH + b * NH + jcol]           = hlast;
    out[(size_t)NB * NT * NH + NB * NH + b * NH + jcol] = cstate;
  }
}

// ================= fallback (round-8 structure, validated) =================
template <bool XBF>
__global__ void __launch_bounds__(256, 1) lstm_seq(
    const float* __restrict__ xf, const unsigned short* __restrict__ xb,
    const float* __restrict__ Wi, const float* __restrict__ Wh,
    float* out, unsigned short* hbuf, unsigned* cnt, unsigned* flags,
    unsigned* epoch)
{
  const int w    = blockIdx.x;
  const int tid  = threadIdx.x;
  const int lane = tid & 63;
  const int wv   = tid >> 6;
  const int c    = lane & 15;
  const int ko   = (lane >> 4) << 3;
  const int n    = (c >> 2) * NH + (w << 2) + (c & 3);

  __shared__ float pre[64][17];

  sv8 bWi[32], bWh[32];
  {
    const float* wi = Wi + (size_t)n * NI + ko;
    const float* wh = Wh + (size_t)n * NH + ko;
#pragma unroll
    for (int kk = 0; kk < 32; ++kk) {
      union { sv8 v; unsigned short u[8]; } pi, ph;
#pragma unroll
      for (int j = 0; j < 8; ++j) {
        pi.u[j] = f2bf(wi[kk * 32 + j]);
        ph.u[j] = f2bf(wh[kk * 32 + j]);
      }
      bWi[kk] = pi.v;
      bWh[kk] = ph.v;
    }
  }

  st2_coh(hbuf + (w << 8) + tid, 0);

  unsigned bar = 1;
  __syncthreads();
  bar_arrive(cnt, flags, bar);
  bar_wait(cnt, flags, epoch, bar);

  const int b    = tid >> 2;
  const int d    = tid & 3;
  const int jcol = (w << 2) + d;
  const int arow = (wv << 4) + c;

  float cstate = 0.0f, hlast = 0.0f;

  for (int t = 0; t < NT; ++t) {
    const unsigned short* hr = hbuf + (t & 1) * NBNH + arow * NH + ko;
    const unsigned short* xr =
        XBF ? (xb + ((size_t)arow * NT + t) * NI + ko) : nullptr;
    const float* xrf =
        XBF ? nullptr : (xf + ((size_t)arow * NT + t) * NI + ko);

    fv4 a0 = {0.f, 0.f, 0.f, 0.f}, a1 = a0, a2 = a0, a3 = a0;
#pragma unroll
    for (int kk = 0; kk < 32; kk += 2) {
      sv8 ax0, ax1;
      if constexpr (XBF) {
        ax0 = *reinterpret_cast<const sv8*>(xr + kk * 32);
        ax1 = *reinterpret_cast<const sv8*>(xr + (kk + 1) * 32);
      } else {
        ax0 = ldcvt8(xrf + kk * 32);
        ax1 = ldcvt8(xrf + (kk + 1) * 32);
      }
      hfrag h0, h1;
      h0.q[0] = ld8_coh(hr + kk * 32);
      h0.q[1] = ld8_coh(hr + kk * 32 + 4);
      h1.q[0] = ld8_coh(hr + (kk + 1) * 32);
      h1.q[1] = ld8_coh(hr + (kk + 1) * 32 + 4);
      a0 = __builtin_amdgcn_mfma_f32_16x16x32_bf16(ax0,  bWi[kk],     a0, 0, 0, 0);
      a1 = __builtin_amdgcn_mfma_f32_16x16x32_bf16(h0.v, bWh[kk],     a1, 0, 0, 0);
      a2 = __builtin_amdgcn_mfma_f32_16x16x32_bf16(ax1,  bWi[kk + 1], a2, 0, 0, 0);
      a3 = __builtin_amdgcn_mfma_f32_16x16x32_bf16(h1.v, bWh[kk + 1], a3, 0, 0, 0);
    }
    fv4 acc = (a0 + a2) + (a1 + a3);

    {
      int prow = (wv << 4) + ((lane >> 4) << 2);
#pragma unroll
      for (int r = 0; r < 4; ++r) pre[prow + r][c] = acc[r];
    }
    __syncthreads();

    float p0 = pre[b][d];
    float p1 = pre[b][4 + d];
    float p2 = pre[b][8 + d];
    float p3 = pre[b][12 + d];
    float it = sigf(sigf(p0));
    float ft = sigf(sigf(p1));
    float ot = sigf(sigf(p2));
    float gt = tanhfast(p3);
    cstate = ft * cstate + it * gt;
    float hv = ot * tanhfast(cstate);
    hlast = hv;

    st2_coh(hbuf + ((t & 1) ^ 1) * NBNH + b * NH + jcol, f2bf(hv));
    __syncthreads();
    ++bar;
    bar_arrive(cnt, flags, bar);
    out[(((size_t)b * NT + t) << 10) + jcol] = hv;
    bar_wait(cnt, flags, epoch, bar);
  }

  out[(size_t)NB * NT * NH + b * NH + jcol]           = hlast;
  out[(size_t)NB * NT * NH + NB * NH + b * NH + jcol] = cstate;
}

extern "C" void kernel_launch(void* const* d_in, const int* in_sizes, int n_in,
                              void* d_out, int out_size, void* d_ws, size_t ws_size,
                              hipStream_t stream) {
  (void)in_sizes; (void)n_in; (void)out_size;
  const float* x  = (const float*)d_in[0];
  const float* Wi = (const float*)d_in[1];
  const float* Wh = (const float*)d_in[2];
  float* out = (float*)d_out;

  // ws layout (every region gated on ws_size before use):
  //   [0,64) cnt | [64,128) epoch | [128,+16K) flags | [+,+256K) hbuf
  //   [+,+8M) Wi bf16 | [+,+64M) x bf16 | [+,+256M) xw bf16
  const size_t EPOCH_OFF = 64;
  const size_t FLAGS_OFF = 128;
  const size_t HBUF_OFF  = FLAGS_OFF + 256 * 64;                    // 16512
  const size_t WIBF_OFF  = HBUF_OFF + (size_t)2 * NBNH * 2;         // 278656
  const size_t XBF_OFF   = WIBF_OFF + (size_t)4096 * 1024 * 2;
  const size_t XW_OFF    = XBF_OFF + (size_t)NB * NT * NI * 2;
  const size_t WS_HOIST  = XW_OFF + (size_t)NB * NT * 4096 * 2;
  const size_t WS_PATHA  = XW_OFF;

  unsigned* cnt = (unsigned*)d_ws;
  unsigned* epoch = (ws_size >= HBUF_OFF)
      ? (unsigned*)((char*)d_ws + EPOCH_OFF) : nullptr;
  unsigned* flags = (ws_size >= HBUF_OFF)
      ? (unsigned*)((char*)d_ws + FLAGS_OFF) : nullptr;
  const bool hbuf_in_ws = ws_size >= WIBF_OFF;

  unsigned short* hbuf = hbuf_in_ws
      ? (unsigned short*)((char*)d_ws + HBUF_OFF)
      : (unsigned short*)(out + (size_t)NB * NT * NH);
  unsigned short* wibf = (unsigned short*)((char*)d_ws + WIBF_OFF);
  unsigned short* xbf  = (unsigned short*)((char*)d_ws + XBF_OFF);
  unsigned short* xw   = (unsigned short*)((char*)d_ws + XW_OFF);

  reset_bar<<<dim3(1), dim3(256), 0, stream>>>(cnt, flags, epoch);

  if (ws_size >= WS_HOIST) {
    int n4x = (NB * NT * NI) / 4;
    cvt_bf16_lin<<<dim3(n4x / 256), dim3(256), 0, stream>>>(x, xbf, n4x);
    int n4w = (4096 * 1024) / 4;
    cvt_bf16_lin<<<dim3(n4w / 256), dim3(256), 0, stream>>>(Wi, wibf, n4w);
    gemm_xw<<<dim3(16384), dim3(256), 0, stream>>>(xbf, wibf, xw);
    lstm_hoist<<<dim3(NWG), dim3(512), 0, stream>>>(xw, Wh, out, hbuf,
                                                    cnt, flags, epoch);
  } else if (ws_size >= WS_PATHA) {
    int n4x = (NB * NT * NI) / 4;
    cvt_bf16_lin<<<dim3(n4x / 256), dim3(256), 0, stream>>>(x, xbf, n4x);
    lstm_seq<true><<<dim3(NWG), dim3(256), 0, stream>>>(
        nullptr, xbf, Wi, Wh, out, hbuf, cnt, flags, epoch);
  } else {
    lstm_seq<false><<<dim3(NWG), dim3(256), 0, stream>>>(
        x, nullptr, Wi, Wh, out, hbuf, cnt, flags, epoch);
  }
}

// Round 13
// 4532.270 us; speedup vs baseline: 1.4881x; 1.0628x over previous
//
#include <hip/hip_runtime.h>

typedef __attribute__((ext_vector_type(8))) short sv8;       // 8 x bf16
typedef __attribute__((ext_vector_type(4))) float fv4;       // MFMA acc

#define NB 64
#define NT 512
#define NI 1024
#define NH 1024
#define NWG 256
#define NBNH (NB * NH)

__device__ __forceinline__ unsigned short f2bf(float f) {
  union { float f; unsigned u; } v; v.f = f;
  unsigned r = v.u + 0x7fffu + ((v.u >> 16) & 1u);  // RNE
  return (unsigned short)(r >> 16);
}
__device__ __forceinline__ float bf2f(unsigned short h) {
  union { unsigned u; float f; } v;
  v.u = ((unsigned)h) << 16;
  return v.f;
}
__device__ __forceinline__ float sigf(float x) {
  return 1.0f / (1.0f + __expf(-x));
}
__device__ __forceinline__ float tanhfast(float x) {
  return 2.0f * sigf(2.0f * x) - 1.0f;
}
__device__ __forceinline__ sv8 ldcvt8(const float* p) {
  float4 a = *reinterpret_cast<const float4*>(p);
  float4 b = *reinterpret_cast<const float4*>(p + 4);
  union { sv8 v; unsigned short u[8]; } r;
  r.u[0] = f2bf(a.x); r.u[1] = f2bf(a.y); r.u[2] = f2bf(a.z); r.u[3] = f2bf(a.w);
  r.u[4] = f2bf(b.x); r.u[5] = f2bf(b.y); r.u[6] = f2bf(b.z); r.u[7] = f2bf(b.w);
  return r.v;
}

// MALL-coherent accessors (agent-scope RELAXED -> sc0 sc1, no cache maint.)
__device__ __forceinline__ unsigned long long ld8_coh(const unsigned short* p) {
  return __hip_atomic_load((const unsigned long long*)p,
                           __ATOMIC_RELAXED, __HIP_MEMORY_SCOPE_AGENT);
}
__device__ __forceinline__ void st2_coh(unsigned short* p, unsigned short v) {
  __hip_atomic_store(p, v, __ATOMIC_RELAXED, __HIP_MEMORY_SCOPE_AGENT);
}
__device__ __forceinline__ void st8_coh(unsigned long long* p, unsigned long long v) {
  __hip_atomic_store(p, v, __ATOMIC_RELAXED, __HIP_MEMORY_SCOPE_AGENT);
}
__device__ __forceinline__ unsigned ld4_coh(const unsigned* p) {
  return __hip_atomic_load(p, __ATOMIC_RELAXED, __HIP_MEMORY_SCOPE_AGENT);
}
__device__ __forceinline__ void st4_coh(unsigned* p, unsigned v) {
  __hip_atomic_store(p, v, __ATOMIC_RELAXED, __HIP_MEMORY_SCOPE_AGENT);
}

union hfrag { sv8 v; unsigned long long q[2]; };

__global__ void reset_bar(unsigned* cnt, unsigned* flags, unsigned* epoch) {
  if (threadIdx.x == 0) { st4_coh(cnt, 0u); if (epoch) st4_coh(epoch, 0u); }
  if (flags) st4_coh(flags + threadIdx.x * 16, 0u);
}

__global__ void cvt_bf16_lin(const float* __restrict__ in,
                             unsigned short* __restrict__ out, int n4) {
  int i = blockIdx.x * blockDim.x + threadIdx.x;
  if (i >= n4) return;
  float4 v = reinterpret_cast<const float4*>(in)[i];
  ushort4 o;
  o.x = f2bf(v.x); o.y = f2bf(v.y); o.z = f2bf(v.z); o.w = f2bf(v.w);
  reinterpret_cast<ushort4*>(out)[i] = o;
}

// ---- two-level fence-free grid barrier + per-step acquire ----
// arrive: WG stores its own flag. wait: WG 0 aggregates 256 flags into one
// epoch word; other WGs poll epoch with one lane/one load. After detection,
// ONE agent-scope ACQUIRE load per WG emits buffer_inv (invalidates this
// CU's L1 + this XCD's L2) so the subsequent PLAIN h loads are L2-cacheable
// yet never stale. (Round 6 proved inv+plain stores functionally correct;
// its cost was per-POLL invs. This is one inv per WG per step.)
__device__ __forceinline__ void bar_arrive(unsigned* cnt, unsigned* flags,
                                           unsigned k) {
  if (flags) {
    if (threadIdx.x == 0) st4_coh(flags + blockIdx.x * 16, k);
  } else {
    if (threadIdx.x == 0)
      __hip_atomic_fetch_add(cnt, 1u, __ATOMIC_RELAXED, __HIP_MEMORY_SCOPE_AGENT);
  }
}
__device__ __forceinline__ void bar_wait(unsigned* cnt, unsigned* flags,
                                         unsigned* epoch, unsigned k) {
  if (flags) {
    if (blockIdx.x == 0) {
      if (threadIdx.x < 64) {
        const unsigned* f = flags + threadIdx.x * 16;
        for (;;) {
          bool ok = (ld4_coh(f)            >= k) & (ld4_coh(f + 64 * 16)  >= k) &
                    (ld4_coh(f + 128 * 16) >= k) & (ld4_coh(f + 192 * 16) >= k);
          if (__all(ok)) break;
          __builtin_amdgcn_s_sleep(1);
        }
        if (threadIdx.x == 0) {
          st4_coh(epoch, k);
          (void)__hip_atomic_load(epoch, __ATOMIC_ACQUIRE,
                                  __HIP_MEMORY_SCOPE_AGENT);  // buffer_inv
        }
      }
    } else {
      if (threadIdx.x == 0) {
        while (ld4_coh(epoch) < k) __builtin_amdgcn_s_sleep(2);
        (void)__hip_atomic_load(epoch, __ATOMIC_ACQUIRE,
                                __HIP_MEMORY_SCOPE_AGENT);    // buffer_inv
      }
    }
  } else {
    if (threadIdx.x == 0) {
      const unsigned target = k * NWG;
      while (ld4_coh(cnt) < target) __builtin_amdgcn_s_sleep(4);
      (void)__hip_atomic_load(cnt, __ATOMIC_ACQUIRE, __HIP_MEMORY_SCOPE_AGENT);
    }
  }
  __syncthreads();
}

// ---- LDS-staged GEMM: xw[s][n] = sum_k x[s][k]*Wi[n][k], bf16 out ----
// 8192 WGs x 256 thr. Tile 128x128, BK=64. 4 waves in 2x2; each wave a
// 64x64 output (4x4 MFMA tiles, acc 64 VGPR). LDS rows padded to 72 elems
// (144 B) -> ds_read_b128 fragment reads are <=2-way bank aliased (free).
__global__ void __launch_bounds__(256) gemm_xw2(
    const unsigned short* __restrict__ xbf,   // [32768][1024] bf16
    const unsigned short* __restrict__ wibf,  // [4096][1024] bf16
    unsigned short* __restrict__ xw)          // [32768][4096] bf16
{
  const int sg   = blockIdx.x & 255;
  const int ng   = blockIdx.x >> 8;          // 0..31
  const int s0   = sg << 7;
  const int n0   = ng << 7;
  const int tid  = threadIdx.x;
  const int lane = tid & 63;
  const int wv   = tid >> 6;
  const int wm   = wv >> 1;
  const int wn   = wv & 1;
  const int c    = lane & 15;
  const int ko   = (lane >> 4) << 3;

  __shared__ unsigned short As[128][72];
  __shared__ unsigned short Bs[128][72];

  const int lrow  = tid >> 1;                // 0..127
  const int lhalf = (tid & 1) << 5;          // 0 or 32

  fv4 acc[4][4];
#pragma unroll
  for (int i = 0; i < 4; ++i)
#pragma unroll
    for (int j = 0; j < 4; ++j) acc[i][j] = fv4{0.f, 0.f, 0.f, 0.f};

  const unsigned short* ag = xbf  + (size_t)(s0 + lrow) * NI + lhalf;
  const unsigned short* bg = wibf + (size_t)(n0 + lrow) * NI + lhalf;

  for (int k0 = 0; k0 < NI; k0 += 64) {
    // stage 128x64 A and B tiles; each thread: 64 contiguous bytes per tile
#pragma unroll
    for (int q = 0; q < 4; ++q) {
      *reinterpret_cast<sv8*>(&As[lrow][lhalf + q * 8]) =
          *reinterpret_cast<const sv8*>(ag + k0 + q * 8);
      *reinterpret_cast<sv8*>(&Bs[lrow][lhalf + q * 8]) =
          *reinterpret_cast<const sv8*>(bg + k0 + q * 8);
    }
    __syncthreads();

#pragma unroll
    for (int kk = 0; kk < 64; kk += 32) {
      sv8 aF[4], bF[4];
#pragma unroll
      for (int i = 0; i < 4; ++i)
        aF[i] = *reinterpret_cast<const sv8*>(&As[(wm << 6) + (i << 4) + c][kk + ko]);
#pragma unroll
      for (int j = 0; j < 4; ++j)
        bF[j] = *reinterpret_cast<const sv8*>(&Bs[(wn << 6) + (j << 4) + c][kk + ko]);
#pragma unroll
      for (int i = 0; i < 4; ++i)
#pragma unroll
        for (int j = 0; j < 4; ++j)
          acc[i][j] = __builtin_amdgcn_mfma_f32_16x16x32_bf16(
              aF[i], bF[j], acc[i][j], 0, 0, 0);
    }
    __syncthreads();   // WAR: LDS reuse next k-step
  }

  // D layout: row = (lane>>4)*4 + r, col = lane&15
#pragma unroll
  for (int i = 0; i < 4; ++i)
#pragma unroll
    for (int j = 0; j < 4; ++j) {
      int row = s0 + (wm << 6) + (i << 4) + ((lane >> 4) << 2);
      int col = n0 + (wn << 6) + (j << 4) + c;
#pragma unroll
      for (int r = 0; r < 4; ++r)
        xw[(size_t)(row + r) * 4096 + col] = f2bf(acc[i][j][r]);
    }
}

// ---- hoisted serial loop: preact = xw[s] + h_t @ Wh^T ----
// 256 WGs x 512 thr. ROUND-13: (a) h loads are PLAIN (L2-cached; per-step
// buffer_inv in bar_wait keeps them fresh) -- h broadcast served by XCD L2s
// instead of MALL; (b) XCD-aware w swizzle so the 8 WGs sharing each xw/out
// 64B line sit on one XCD (FETCH /8, out write-combining).
__global__ void __launch_bounds__(512, 1) lstm_hoist(
    const unsigned short* __restrict__ xw,
    const float* __restrict__ Wh,
    float* out,
    unsigned short* hbuf,
    unsigned* cnt, unsigned* flags, unsigned* epoch)
{
  const int w    = ((blockIdx.x & 7) << 5) | (blockIdx.x >> 3);  // XCD swizzle
  const int tid  = threadIdx.x;
  const int lane = tid & 63;
  const int wv   = tid >> 6;
  const int half = wv >> 2;
  const int wq   = wv & 3;
  const int c    = lane & 15;
  const int ko   = (lane >> 4) << 3;
  const int n    = (c >> 2) * NH + (w << 2) + (c & 3);

  __shared__ float pre2[2][64][17];

  sv8 bWh[16];
  {
    const float* wh = Wh + (size_t)n * NH + half * 512 + ko;
#pragma unroll
    for (int kk = 0; kk < 16; ++kk) {
      union { sv8 v; unsigned short u[8]; } ph;
#pragma unroll
      for (int j = 0; j < 8; ++j) ph.u[j] = f2bf(wh[kk * 32 + j]);
      bWh[kk] = ph.v;
    }
  }

  if (tid < 256) st2_coh(hbuf + (w << 8) + tid, 0);

  unsigned bar = 1;
  __syncthreads();
  bar_arrive(cnt, flags, bar);
  bar_wait(cnt, flags, epoch, bar);

  const int b    = tid >> 2;        // gate threads: tid < 256
  const int d    = tid & 3;
  const int jcol = (w << 2) + d;
  const int arow = (wq << 4) + c;

  float cstate = 0.0f, hlast = 0.0f;

  unsigned short xwc[4] = {0, 0, 0, 0};
  if (tid < 256) {
    const unsigned short* xwp = xw + ((size_t)b * NT + 0) * 4096 + jcol;
#pragma unroll
    for (int g = 0; g < 4; ++g) xwc[g] = xwp[g * 1024];
  }

  for (int t = 0; t < NT; ++t) {
    const unsigned short* hr =
        hbuf + (t & 1) * NBNH + arow * NH + half * 512 + ko;

    // plain (cacheable) h loads -- XCD L2 serves the broadcast; freshness
    // guaranteed by the per-step buffer_inv in bar_wait.
    sv8 hh[16];
#pragma unroll
    for (int kk = 0; kk < 16; ++kk)
      hh[kk] = *reinterpret_cast<const sv8*>(hr + kk * 32);

    fv4 a0 = {0.f, 0.f, 0.f, 0.f}, a1 = a0;
#pragma unroll
    for (int kk = 0; kk < 16; kk += 2) {
      a0 = __builtin_amdgcn_mfma_f32_16x16x32_bf16(hh[kk],     bWh[kk],     a0, 0, 0, 0);
      a1 = __builtin_amdgcn_mfma_f32_16x16x32_bf16(hh[kk + 1], bWh[kk + 1], a1, 0, 0, 0);
    }
    fv4 acc = a0 + a1;

    // D layout: row = (lane>>4)*4 + r, col = lane&15
    {
      int prow = (wq << 4) + ((lane >> 4) << 2);
#pragma unroll
      for (int r = 0; r < 4; ++r) pre2[half][prow + r][c] = acc[r];
    }
    __syncthreads();

    float hv = 0.0f;
    if (tid < 256) {
      float p0 = pre2[0][b][d]      + pre2[1][b][d]      + bf2f(xwc[0]);
      float p1 = pre2[0][b][4 + d]  + pre2[1][b][4 + d]  + bf2f(xwc[1]);
      float p2 = pre2[0][b][8 + d]  + pre2[1][b][8 + d]  + bf2f(xwc[2]);
      float p3 = pre2[0][b][12 + d] + pre2[1][b][12 + d] + bf2f(xwc[3]);
      float it = sigf(sigf(p0));
      float ft = sigf(sigf(p1));
      float ot = sigf(sigf(p2));
      float gt = tanhfast(p3);
      cstate = ft * cstate + it * gt;
      hv = ot * tanhfast(cstate);
      hlast = hv;
      // pack 4 neighbors' bf16 h into one 8B coherent (write-through) store
      int hbi = (int)f2bf(hv);
      int h1 = __shfl_down(hbi, 1);
      int h2 = __shfl_down(hbi, 2);
      int h3 = __shfl_down(hbi, 3);
      if (d == 0) {
        unsigned long long pk =
            (unsigned long long)(unsigned short)hbi |
            ((unsigned long long)(unsigned short)h1 << 16) |
            ((unsigned long long)(unsigned short)h2 << 32) |
            ((unsigned long long)(unsigned short)h3 << 48);
        st8_coh((unsigned long long*)(hbuf + ((t & 1) ^ 1) * NBNH +
                                      b * NH + (w << 2)), pk);
      }
    }
    __syncthreads();                 // drains h stores (vmcnt 0)
    ++bar;
    bar_arrive(cnt, flags, bar);
    if (tid < 256) {
      out[(((size_t)b * NT + t) << 10) + jcol] = hv;
      if (t + 1 < NT) {
        const unsigned short* xwp = xw + ((size_t)b * NT + t + 1) * 4096 + jcol;
#pragma unroll
        for (int g = 0; g < 4; ++g) xwc[g] = xwp[g * 1024];
      }
    }
    bar_wait(cnt, flags, epoch, bar);
  }

  if (tid < 256) {
    out[(size_t)NB * NT * NH + b * NH + jcol]           = hlast;
    out[(size_t)NB * NT * NH + NB * NH + b * NH + jcol] = cstate;
  }
}

// ================= fallback (round-8 structure, validated) =================
template <bool XBF>
__global__ void __launch_bounds__(256, 1) lstm_seq(
    const float* __restrict__ xf, const unsigned short* __restrict__ xb,
    const float* __restrict__ Wi, const float* __restrict__ Wh,
    float* out, unsigned short* hbuf, unsigned* cnt, unsigned* flags,
    unsigned* epoch)
{
  const int w    = blockIdx.x;
  const int tid  = threadIdx.x;
  const int lane = tid & 63;
  const int wv   = tid >> 6;
  const int c    = lane & 15;
  const int ko   = (lane >> 4) << 3;
  const int n    = (c >> 2) * NH + (w << 2) + (c & 3);

  __shared__ float pre[64][17];

  sv8 bWi[32], bWh[32];
  {
    const float* wi = Wi + (size_t)n * NI + ko;
    const float* wh = Wh + (size_t)n * NH + ko;
#pragma unroll
    for (int kk = 0; kk < 32; ++kk) {
      union { sv8 v; unsigned short u[8]; } pi, ph;
#pragma unroll
      for (int j = 0; j < 8; ++j) {
        pi.u[j] = f2bf(wi[kk * 32 + j]);
        ph.u[j] = f2bf(wh[kk * 32 + j]);
      }
      bWi[kk] = pi.v;
      bWh[kk] = ph.v;
    }
  }

  st2_coh(hbuf + (w << 8) + tid, 0);

  unsigned bar = 1;
  __syncthreads();
  bar_arrive(cnt, flags, bar);
  bar_wait(cnt, flags, epoch, bar);

  const int b    = tid >> 2;
  const int d    = tid & 3;
  const int jcol = (w << 2) + d;
  const int arow = (wv << 4) + c;

  float cstate = 0.0f, hlast = 0.0f;

  for (int t = 0; t < NT; ++t) {
    const unsigned short* hr = hbuf + (t & 1) * NBNH + arow * NH + ko;
    const unsigned short* xr =
        XBF ? (xb + ((size_t)arow * NT + t) * NI + ko) : nullptr;
    const float* xrf =
        XBF ? nullptr : (xf + ((size_t)arow * NT + t) * NI + ko);

    fv4 a0 = {0.f, 0.f, 0.f, 0.f}, a1 = a0, a2 = a0, a3 = a0;
#pragma unroll
    for (int kk = 0; kk < 32; kk += 2) {
      sv8 ax0, ax1;
      if constexpr (XBF) {
        ax0 = *reinterpret_cast<const sv8*>(xr + kk * 32);
        ax1 = *reinterpret_cast<const sv8*>(xr + (kk + 1) * 32);
      } else {
        ax0 = ldcvt8(xrf + kk * 32);
        ax1 = ldcvt8(xrf + (kk + 1) * 32);
      }
      hfrag h0, h1;
      h0.q[0] = ld8_coh(hr + kk * 32);
      h0.q[1] = ld8_coh(hr + kk * 32 + 4);
      h1.q[0] = ld8_coh(hr + (kk + 1) * 32);
      h1.q[1] = ld8_coh(hr + (kk + 1) * 32 + 4);
      a0 = __builtin_amdgcn_mfma_f32_16x16x32_bf16(ax0,  bWi[kk],     a0, 0, 0, 0);
      a1 = __builtin_amdgcn_mfma_f32_16x16x32_bf16(h0.v, bWh[kk],     a1, 0, 0, 0);
      a2 = __builtin_amdgcn_mfma_f32_16x16x32_bf16(ax1,  bWi[kk + 1], a2, 0, 0, 0);
      a3 = __builtin_amdgcn_mfma_f32_16x16x32_bf16(h1.v, bWh[kk + 1], a3, 0, 0, 0);
    }
    fv4 acc = (a0 + a2) + (a1 + a3);

    {
      int prow = (wv << 4) + ((lane >> 4) << 2);
#pragma unroll
      for (int r = 0; r < 4; ++r) pre[prow + r][c] = acc[r];
    }
    __syncthreads();

    float p0 = pre[b][d];
    float p1 = pre[b][4 + d];
    float p2 = pre[b][8 + d];
    float p3 = pre[b][12 + d];
    float it = sigf(sigf(p0));
    float ft = sigf(sigf(p1));
    float ot = sigf(sigf(p2));
    float gt = tanhfast(p3);
    cstate = ft * cstate + it * gt;
    float hv = ot * tanhfast(cstate);
    hlast = hv;

    st2_coh(hbuf + ((t & 1) ^ 1) * NBNH + b * NH + jcol, f2bf(hv));
    __syncthreads();
    ++bar;
    bar_arrive(cnt, flags, bar);
    out[(((size_t)b * NT + t) << 10) + jcol] = hv;
    bar_wait(cnt, flags, epoch, bar);
  }

  out[(size_t)NB * NT * NH + b * NH + jcol]           = hlast;
  out[(size_t)NB * NT * NH + NB * NH + b * NH + jcol] = cstate;
}

extern "C" void kernel_launch(void* const* d_in, const int* in_sizes, int n_in,
                              void* d_out, int out_size, void* d_ws, size_t ws_size,
                              hipStream_t stream) {
  (void)in_sizes; (void)n_in; (void)out_size;
  const float* x  = (const float*)d_in[0];
  const float* Wi = (const float*)d_in[1];
  const float* Wh = (const float*)d_in[2];
  float* out = (float*)d_out;

  // ws layout (every region gated on ws_size before use):
  //   [0,64) cnt | [64,128) epoch | [128,+16K) flags | [+,+256K) hbuf
  //   [+,+8M) Wi bf16 | [+,+64M) x bf16 | [+,+256M) xw bf16
  const size_t EPOCH_OFF = 64;
  const size_t FLAGS_OFF = 128;
  const size_t HBUF_OFF  = FLAGS_OFF + 256 * 64;                    // 16512
  const size_t WIBF_OFF  = HBUF_OFF + (size_t)2 * NBNH * 2;         // 278656
  const size_t XBF_OFF   = WIBF_OFF + (size_t)4096 * 1024 * 2;
  const size_t XW_OFF    = XBF_OFF + (size_t)NB * NT * NI * 2;
  const size_t WS_HOIST  = XW_OFF + (size_t)NB * NT * 4096 * 2;
  const size_t WS_PATHA  = XW_OFF;

  unsigned* cnt = (unsigned*)d_ws;
  unsigned* epoch = (ws_size >= HBUF_OFF)
      ? (unsigned*)((char*)d_ws + EPOCH_OFF) : nullptr;
  unsigned* flags = (ws_size >= HBUF_OFF)
      ? (unsigned*)((char*)d_ws + FLAGS_OFF) : nullptr;
  const bool hbuf_in_ws = ws_size >= WIBF_OFF;

  unsigned short* hbuf = hbuf_in_ws
      ? (unsigned short*)((char*)d_ws + HBUF_OFF)
      : (unsigned short*)(out + (size_t)NB * NT * NH);
  unsigned short* wibf = (unsigned short*)((char*)d_ws + WIBF_OFF);
  unsigned short* xbf  = (unsigned short*)((char*)d_ws + XBF_OFF);
  unsigned short* xw   = (unsigned short*)((char*)d_ws + XW_OFF);

  reset_bar<<<dim3(1), dim3(256), 0, stream>>>(cnt, flags, epoch);

  if (ws_size >= WS_HOIST) {
    int n4x = (NB * NT * NI) / 4;
    cvt_bf16_lin<<<dim3(n4x / 256), dim3(256), 0, stream>>>(x, xbf, n4x);
    int n4w = (4096 * 1024) / 4;
    cvt_bf16_lin<<<dim3(n4w / 256), dim3(256), 0, stream>>>(Wi, wibf, n4w);
    gemm_xw2<<<dim3(8192), dim3(256), 0, stream>>>(xbf, wibf, xw);
    lstm_hoist<<<dim3(NWG), dim3(512), 0, stream>>>(xw, Wh, out, hbuf,
                                                    cnt, flags, epoch);
  } else if (ws_size >= WS_PATHA) {
    int n4x = (NB * NT * NI) / 4;
    cvt_bf16_lin<<<dim3(n4x / 256), dim3(256), 0, stream>>>(x, xbf, n4x);
    lstm_seq<true><<<dim3(NWG), dim3(256), 0, stream>>>(
        nullptr, xbf, Wi, Wh, out, hbuf, cnt, flags, epoch);
  } else {
    lstm_seq<false><<<dim3(NWG), dim3(256), 0, stream>>>(
        x, nullptr, Wi, Wh, out, hbuf, cnt, flags, epoch);
  }
}

// Round 14
// 3750.524 us; speedup vs baseline: 1.7983x; 1.2084x over previous
//
#include <hip/hip_runtime.h>

typedef __attribute__((ext_vector_type(8))) short sv8;       // 8 x bf16
typedef __attribute__((ext_vector_type(4))) float fv4;       // MFMA acc
typedef __attribute__((ext_vector_type(4))) unsigned int uv4;// 16B payload

#define NB 64
#define NT 512
#define NI 1024
#define NH 1024
#define NBNH (NB * NH)
#define HWG 128            // lstm_hoist workgroups (8 h-cols each)

__device__ __forceinline__ unsigned short f2bf(float f) {
  union { float f; unsigned u; } v; v.f = f;
  unsigned r = v.u + 0x7fffu + ((v.u >> 16) & 1u);  // RNE
  return (unsigned short)(r >> 16);
}
__device__ __forceinline__ float bf2f(unsigned short h) {
  union { unsigned u; float f; } v;
  v.u = ((unsigned)h) << 16;
  return v.f;
}
__device__ __forceinline__ float sigf(float x) {
  return 1.0f / (1.0f + __expf(-x));
}
__device__ __forceinline__ float tanhfast(float x) {
  return 2.0f * sigf(2.0f * x) - 1.0f;
}
__device__ __forceinline__ sv8 ldcvt8(const float* p) {
  float4 a = *reinterpret_cast<const float4*>(p);
  float4 b = *reinterpret_cast<const float4*>(p + 4);
  union { sv8 v; unsigned short u[8]; } r;
  r.u[0] = f2bf(a.x); r.u[1] = f2bf(a.y); r.u[2] = f2bf(a.z); r.u[3] = f2bf(a.w);
  r.u[4] = f2bf(b.x); r.u[5] = f2bf(b.y); r.u[6] = f2bf(b.z); r.u[7] = f2bf(b.w);
  return r.v;
}

// MALL-coherent accessors (agent-scope RELAXED -> sc0 sc1, no cache maint.)
__device__ __forceinline__ unsigned long long ld8_coh(const unsigned short* p) {
  return __hip_atomic_load((const unsigned long long*)p,
                           __ATOMIC_RELAXED, __HIP_MEMORY_SCOPE_AGENT);
}
__device__ __forceinline__ void st2_coh(unsigned short* p, unsigned short v) {
  __hip_atomic_store(p, v, __ATOMIC_RELAXED, __HIP_MEMORY_SCOPE_AGENT);
}
__device__ __forceinline__ void st8_coh(unsigned long long* p, unsigned long long v) {
  __hip_atomic_store(p, v, __ATOMIC_RELAXED, __HIP_MEMORY_SCOPE_AGENT);
}
__device__ __forceinline__ unsigned ld4_coh(const unsigned* p) {
  return __hip_atomic_load(p, __ATOMIC_RELAXED, __HIP_MEMORY_SCOPE_AGENT);
}
__device__ __forceinline__ void st4_coh(unsigned* p, unsigned v) {
  __hip_atomic_store(p, v, __ATOMIC_RELAXED, __HIP_MEMORY_SCOPE_AGENT);
}

union hfrag { sv8 v; unsigned long long q[2]; };

// 16 x 16B coherent loads (64B apart), single waitcnt (proven round 12).
__device__ __forceinline__ void ld_h_block(const unsigned short* hr, uv4 hh[16]) {
  asm volatile(
      "global_load_dwordx4 %0, %16, off sc0 sc1\n\t"
      "global_load_dwordx4 %1, %16, off offset:64 sc0 sc1\n\t"
      "global_load_dwordx4 %2, %16, off offset:128 sc0 sc1\n\t"
      "global_load_dwordx4 %3, %16, off offset:192 sc0 sc1\n\t"
      "global_load_dwordx4 %4, %16, off offset:256 sc0 sc1\n\t"
      "global_load_dwordx4 %5, %16, off offset:320 sc0 sc1\n\t"
      "global_load_dwordx4 %6, %16, off offset:384 sc0 sc1\n\t"
      "global_load_dwordx4 %7, %16, off offset:448 sc0 sc1\n\t"
      "global_load_dwordx4 %8, %16, off offset:512 sc0 sc1\n\t"
      "global_load_dwordx4 %9, %16, off offset:576 sc0 sc1\n\t"
      "global_load_dwordx4 %10, %16, off offset:640 sc0 sc1\n\t"
      "global_load_dwordx4 %11, %16, off offset:704 sc0 sc1\n\t"
      "global_load_dwordx4 %12, %16, off offset:768 sc0 sc1\n\t"
      "global_load_dwordx4 %13, %16, off offset:832 sc0 sc1\n\t"
      "global_load_dwordx4 %14, %16, off offset:896 sc0 sc1\n\t"
      "global_load_dwordx4 %15, %16, off offset:960 sc0 sc1\n\t"
      "s_waitcnt vmcnt(0)"
      : "=&v"(hh[0]), "=&v"(hh[1]), "=&v"(hh[2]), "=&v"(hh[3]),
        "=&v"(hh[4]), "=&v"(hh[5]), "=&v"(hh[6]), "=&v"(hh[7]),
        "=&v"(hh[8]), "=&v"(hh[9]), "=&v"(hh[10]), "=&v"(hh[11]),
        "=&v"(hh[12]), "=&v"(hh[13]), "=&v"(hh[14]), "=&v"(hh[15])
      : "v"(hr)
      : "memory");
}

__global__ void reset_bar(unsigned* cnt, unsigned* flags, unsigned* epoch) {
  if (threadIdx.x == 0) { st4_coh(cnt, 0u); if (epoch) st4_coh(epoch, 0u); }
  if (flags) st4_coh(flags + threadIdx.x * 16, 0u);
}

__global__ void cvt_bf16_lin(const float* __restrict__ in,
                             unsigned short* __restrict__ out, int n4) {
  int i = blockIdx.x * blockDim.x + threadIdx.x;
  if (i >= n4) return;
  float4 v = reinterpret_cast<const float4*>(in)[i];
  ushort4 o;
  o.x = f2bf(v.x); o.y = f2bf(v.y); o.z = f2bf(v.z); o.w = f2bf(v.w);
  reinterpret_cast<ushort4*>(out)[i] = o;
}

// ---- two-level fence-free grid barrier (round-12 form, NO inv) ----
// arrive: WG stores its own flag. wait: WG 0 aggregates NWGS flags into one
// epoch word; other WGs poll epoch with one lane/one load.
template <int NWGS>
__device__ __forceinline__ void bar_arrive(unsigned* cnt, unsigned* flags,
                                           unsigned k) {
  if (flags) {
    if (threadIdx.x == 0) st4_coh(flags + blockIdx.x * 16, k);
  } else {
    if (threadIdx.x == 0)
      __hip_atomic_fetch_add(cnt, 1u, __ATOMIC_RELAXED, __HIP_MEMORY_SCOPE_AGENT);
  }
}
template <int NWGS>
__device__ __forceinline__ void bar_wait(unsigned* cnt, unsigned* flags,
                                         unsigned* epoch, unsigned k) {
  if (flags) {
    if (blockIdx.x == 0) {
      if (threadIdx.x < 64) {
        const unsigned* f = flags + threadIdx.x * 16;
        for (;;) {
          bool ok = true;
#pragma unroll
          for (int q = 0; q < NWGS / 64; ++q)
            ok &= (ld4_coh(f + q * 64 * 16) >= k);
          if (__all(ok)) break;
          __builtin_amdgcn_s_sleep(1);
        }
        if (threadIdx.x == 0) st4_coh(epoch, k);
      }
    } else {
      if (threadIdx.x == 0) {
        while (ld4_coh(epoch) < k) __builtin_amdgcn_s_sleep(2);
      }
    }
  } else {
    if (threadIdx.x == 0) {
      const unsigned target = k * NWGS;
      while (ld4_coh(cnt) < target) __builtin_amdgcn_s_sleep(4);
    }
  }
  __syncthreads();
}

// ---- LDS-staged GEMM (validated round 13): xw = x @ Wi^T, bf16 out ----
__global__ void __launch_bounds__(256) gemm_xw2(
    const unsigned short* __restrict__ xbf,
    const unsigned short* __restrict__ wibf,
    unsigned short* __restrict__ xw)
{
  const int sg   = blockIdx.x & 255;
  const int ng   = blockIdx.x >> 8;
  const int s0   = sg << 7;
  const int n0   = ng << 7;
  const int tid  = threadIdx.x;
  const int lane = tid & 63;
  const int wv   = tid >> 6;
  const int wm   = wv >> 1;
  const int wn   = wv & 1;
  const int c    = lane & 15;
  const int ko   = (lane >> 4) << 3;

  __shared__ unsigned short As[128][72];
  __shared__ unsigned short Bs[128][72];

  const int lrow  = tid >> 1;
  const int lhalf = (tid & 1) << 5;

  fv4 acc[4][4];
#pragma unroll
  for (int i = 0; i < 4; ++i)
#pragma unroll
    for (int j = 0; j < 4; ++j) acc[i][j] = fv4{0.f, 0.f, 0.f, 0.f};

  const unsigned short* ag = xbf  + (size_t)(s0 + lrow) * NI + lhalf;
  const unsigned short* bg = wibf + (size_t)(n0 + lrow) * NI + lhalf;

  for (int k0 = 0; k0 < NI; k0 += 64) {
#pragma unroll
    for (int q = 0; q < 4; ++q) {
      *reinterpret_cast<sv8*>(&As[lrow][lhalf + q * 8]) =
          *reinterpret_cast<const sv8*>(ag + k0 + q * 8);
      *reinterpret_cast<sv8*>(&Bs[lrow][lhalf + q * 8]) =
          *reinterpret_cast<const sv8*>(bg + k0 + q * 8);
    }
    __syncthreads();

#pragma unroll
    for (int kk = 0; kk < 64; kk += 32) {
      sv8 aF[4], bF[4];
#pragma unroll
      for (int i = 0; i < 4; ++i)
        aF[i] = *reinterpret_cast<const sv8*>(&As[(wm << 6) + (i << 4) + c][kk + ko]);
#pragma unroll
      for (int j = 0; j < 4; ++j)
        bF[j] = *reinterpret_cast<const sv8*>(&Bs[(wn << 6) + (j << 4) + c][kk + ko]);
#pragma unroll
      for (int i = 0; i < 4; ++i)
#pragma unroll
        for (int j = 0; j < 4; ++j)
          acc[i][j] = __builtin_amdgcn_mfma_f32_16x16x32_bf16(
              aF[i], bF[j], acc[i][j], 0, 0, 0);
    }
    __syncthreads();
  }

#pragma unroll
  for (int i = 0; i < 4; ++i)
#pragma unroll
    for (int j = 0; j < 4; ++j) {
      int row = s0 + (wm << 6) + (i << 4) + ((lane >> 4) << 2);
      int col = n0 + (wn << 6) + (j << 4) + c;
#pragma unroll
      for (int r = 0; r < 4; ++r)
        xw[(size_t)(row + r) * 4096 + col] = f2bf(acc[i][j][r]);
    }
}

// ---- hoisted serial loop: preact = xw[s] + h_t @ Wh^T ----
// ROUND-14: 128 WGs x 512 thr; each WG owns 8 h-cols (32 preact cols as
// 2 col-tiles). Wave (half = wv>>2, wq = wv&3): batch rows 16wq..+15,
// K-half 512. Per-WG coherent h volume unchanged (no duplication); grid
// total halves to 16 MB/step. B-frags 128 VGPR/lane; launch_bounds(512,2)
// caps at 256 VGPR so all 8 waves stay resident.
__global__ void __launch_bounds__(512, 2) lstm_hoist(
    const unsigned short* __restrict__ xw,
    const float* __restrict__ Wh,
    float* out,
    unsigned short* hbuf,
    unsigned* cnt, unsigned* flags, unsigned* epoch)
{
  const int w    = ((blockIdx.x & 7) << 4) | (blockIdx.x >> 3);  // XCD swizzle
  const int tid  = threadIdx.x;
  const int lane = tid & 63;
  const int wv   = tid >> 6;
  const int half = wv >> 2;
  const int wq   = wv & 3;
  const int c    = lane & 15;
  const int ko   = (lane >> 4) << 3;

  __shared__ float pre2[2][64][33];   // 2 k-halves x 64 batch x 32 cols (+pad)

  // weight fragments: 2 col-tiles x 16 k-steps = 128 VGPR/lane
  sv8 bWh[2][16];
#pragma unroll
  for (int ct = 0; ct < 2; ++ct) {
    int j = (ct << 4) + c;                       // WG-local preact col index
    int n = ((j >> 3) << 10) + (w << 3) + (j & 7);  // g*1024 + w*8 + d
    const float* wh = Wh + (size_t)n * NH + half * 512 + ko;
#pragma unroll
    for (int kk = 0; kk < 16; ++kk) {
      union { sv8 v; unsigned short u[8]; } ph;
#pragma unroll
      for (int jj = 0; jj < 8; ++jj) ph.u[jj] = f2bf(wh[kk * 32 + jj]);
      bWh[ct][kk] = ph.v;
    }
  }

  // zero h_0 (buffer 0): 128 WGs x 512 thr == NBNH exactly
  st2_coh(hbuf + (w << 9) + tid, 0);

  unsigned bar = 1;
  __syncthreads();
  bar_arrive<HWG>(cnt, flags, bar);
  bar_wait<HWG>(cnt, flags, epoch, bar);

  const int b    = tid >> 3;        // gate phase: all 512 threads
  const int d    = tid & 7;
  const int jcol = (w << 3) + d;
  const int arow = (wq << 4) + c;

  float cstate = 0.0f, hlast = 0.0f;

  unsigned short xwc[4] = {0, 0, 0, 0};
  {
    const unsigned short* xwp = xw + ((size_t)b * NT + 0) * 4096 + jcol;
#pragma unroll
    for (int g = 0; g < 4; ++g) xwc[g] = xwp[g * 1024];
  }

  for (int t = 0; t < NT; ++t) {
    const unsigned short* hr =
        hbuf + (t & 1) * NBNH + arow * NH + half * 512 + ko;

    uv4 hh[16];
    ld_h_block(hr, hh);

    fv4 a0 = {0.f, 0.f, 0.f, 0.f}, a1 = a0;
#pragma unroll
    for (int kk = 0; kk < 16; ++kk) {
      union { uv4 u; sv8 s; } ca;
      ca.u = hh[kk];
      a0 = __builtin_amdgcn_mfma_f32_16x16x32_bf16(ca.s, bWh[0][kk], a0, 0, 0, 0);
      a1 = __builtin_amdgcn_mfma_f32_16x16x32_bf16(ca.s, bWh[1][kk], a1, 0, 0, 0);
    }

    // D layout: row = (lane>>4)*4 + r, col = lane&15
    {
      int prow = (wq << 4) + ((lane >> 4) << 2);
#pragma unroll
      for (int r = 0; r < 4; ++r) {
        pre2[half][prow + r][c]      = a0[r];
        pre2[half][prow + r][16 + c] = a1[r];
      }
    }
    __syncthreads();

    // gates: thread (b,d) reads WG-local col j = g*8 + d
    float p0 = pre2[0][b][d]      + pre2[1][b][d]      + bf2f(xwc[0]);
    float p1 = pre2[0][b][8 + d]  + pre2[1][b][8 + d]  + bf2f(xwc[1]);
    float p2 = pre2[0][b][16 + d] + pre2[1][b][16 + d] + bf2f(xwc[2]);
    float p3 = pre2[0][b][24 + d] + pre2[1][b][24 + d] + bf2f(xwc[3]);
    float it = sigf(sigf(p0));
    float ft = sigf(sigf(p1));
    float ot = sigf(sigf(p2));
    float gt = tanhfast(p3);
    cstate = ft * cstate + it * gt;
    float hv = ot * tanhfast(cstate);
    hlast = hv;

    // pack 4 neighbors' bf16 h into one 8B coherent store
    {
      int hbi = (int)f2bf(hv);
      int h1 = __shfl_down(hbi, 1);
      int h2 = __shfl_down(hbi, 2);
      int h3 = __shfl_down(hbi, 3);
      if ((d & 3) == 0) {
        unsigned long long pk =
            (unsigned long long)(unsigned short)hbi |
            ((unsigned long long)(unsigned short)h1 << 16) |
            ((unsigned long long)(unsigned short)h2 << 32) |
            ((unsigned long long)(unsigned short)h3 << 48);
        st8_coh((unsigned long long*)(hbuf + ((t & 1) ^ 1) * NBNH +
                                      b * NH + (w << 3) + (d & 4)), pk);
      }
    }
    __syncthreads();                 // drains h stores (vmcnt 0)
    ++bar;
    bar_arrive<HWG>(cnt, flags, bar);
    // hidden under barrier spin:
    out[(((size_t)b * NT + t) << 10) + jcol] = hv;
    if (t + 1 < NT) {
      const unsigned short* xwp = xw + ((size_t)b * NT + t + 1) * 4096 + jcol;
#pragma unroll
      for (int g = 0; g < 4; ++g) xwc[g] = xwp[g * 1024];
    }
    bar_wait<HWG>(cnt, flags, epoch, bar);
  }

  out[(size_t)NB * NT * NH + b * NH + jcol]           = hlast;
  out[(size_t)NB * NT * NH + NB * NH + b * NH + jcol] = cstate;
}

// ================= fallback (round-8 structure, validated) =================
template <bool XBF>
__global__ void __launch_bounds__(256, 1) lstm_seq(
    const float* __restrict__ xf, const unsigned short* __restrict__ xb,
    const float* __restrict__ Wi, const float* __restrict__ Wh,
    float* out, unsigned short* hbuf, unsigned* cnt, unsigned* flags,
    unsigned* epoch)
{
  const int w    = blockIdx.x;
  const int tid  = threadIdx.x;
  const int lane = tid & 63;
  const int wv   = tid >> 6;
  const int c    = lane & 15;
  const int ko   = (lane >> 4) << 3;
  const int n    = (c >> 2) * NH + (w << 2) + (c & 3);

  __shared__ float pre[64][17];

  sv8 bWi[32], bWh[32];
  {
    const float* wi = Wi + (size_t)n * NI + ko;
    const float* wh = Wh + (size_t)n * NH + ko;
#pragma unroll
    for (int kk = 0; kk < 32; ++kk) {
      union { sv8 v; unsigned short u[8]; } pi, ph;
#pragma unroll
      for (int j = 0; j < 8; ++j) {
        pi.u[j] = f2bf(wi[kk * 32 + j]);
        ph.u[j] = f2bf(wh[kk * 32 + j]);
      }
      bWi[kk] = pi.v;
      bWh[kk] = ph.v;
    }
  }

  st2_coh(hbuf + (w << 8) + tid, 0);

  unsigned bar = 1;
  __syncthreads();
  bar_arrive<256>(cnt, flags, bar);
  bar_wait<256>(cnt, flags, epoch, bar);

  const int b    = tid >> 2;
  const int d    = tid & 3;
  const int jcol = (w << 2) + d;
  const int arow = (wv << 4) + c;

  float cstate = 0.0f, hlast = 0.0f;

  for (int t = 0; t < NT; ++t) {
    const unsigned short* hr = hbuf + (t & 1) * NBNH + arow * NH + ko;
    const unsigned short* xr =
        XBF ? (xb + ((size_t)arow * NT + t) * NI + ko) : nullptr;
    const float* xrf =
        XBF ? nullptr : (xf + ((size_t)arow * NT + t) * NI + ko);

    fv4 a0 = {0.f, 0.f, 0.f, 0.f}, a1 = a0, a2 = a0, a3 = a0;
#pragma unroll
    for (int kk = 0; kk < 32; kk += 2) {
      sv8 ax0, ax1;
      if constexpr (XBF) {
        ax0 = *reinterpret_cast<const sv8*>(xr + kk * 32);
        ax1 = *reinterpret_cast<const sv8*>(xr + (kk + 1) * 32);
      } else {
        ax0 = ldcvt8(xrf + kk * 32);
        ax1 = ldcvt8(xrf + (kk + 1) * 32);
      }
      hfrag h0, h1;
      h0.q[0] = ld8_coh(hr + kk * 32);
      h0.q[1] = ld8_coh(hr + kk * 32 + 4);
      h1.q[0] = ld8_coh(hr + (kk + 1) * 32);
      h1.q[1] = ld8_coh(hr + (kk + 1) * 32 + 4);
      a0 = __builtin_amdgcn_mfma_f32_16x16x32_bf16(ax0,  bWi[kk],     a0, 0, 0, 0);
      a1 = __builtin_amdgcn_mfma_f32_16x16x32_bf16(h0.v, bWh[kk],     a1, 0, 0, 0);
      a2 = __builtin_amdgcn_mfma_f32_16x16x32_bf16(ax1,  bWi[kk + 1], a2, 0, 0, 0);
      a3 = __builtin_amdgcn_mfma_f32_16x16x32_bf16(h1.v, bWh[kk + 1], a3, 0, 0, 0);
    }
    fv4 acc = (a0 + a2) + (a1 + a3);

    {
      int prow = (wv << 4) + ((lane >> 4) << 2);
#pragma unroll
      for (int r = 0; r < 4; ++r) pre[prow + r][c] = acc[r];
    }
    __syncthreads();

    float p0 = pre[b][d];
    float p1 = pre[b][4 + d];
    float p2 = pre[b][8 + d];
    float p3 = pre[b][12 + d];
    float it = sigf(sigf(p0));
    float ft = sigf(sigf(p1));
    float ot = sigf(sigf(p2));
    float gt = tanhfast(p3);
    cstate = ft * cstate + it * gt;
    float hv = ot * tanhfast(cstate);
    hlast = hv;

    st2_coh(hbuf + ((t & 1) ^ 1) * NBNH + b * NH + jcol, f2bf(hv));
    __syncthreads();
    ++bar;
    bar_arrive<256>(cnt, flags, bar);
    out[(((size_t)b * NT + t) << 10) + jcol] = hv;
    bar_wait<256>(cnt, flags, epoch, bar);
  }

  out[(size_t)NB * NT * NH + b * NH + jcol]           = hlast;
  out[(size_t)NB * NT * NH + NB * NH + b * NH + jcol] = cstate;
}

extern "C" void kernel_launch(void* const* d_in, const int* in_sizes, int n_in,
                              void* d_out, int out_size, void* d_ws, size_t ws_size,
                              hipStream_t stream) {
  (void)in_sizes; (void)n_in; (void)out_size;
  const float* x  = (const float*)d_in[0];
  const float* Wi = (const float*)d_in[1];
  const float* Wh = (const float*)d_in[2];
  float* out = (float*)d_out;

  const size_t EPOCH_OFF = 64;
  const size_t FLAGS_OFF = 128;
  const size_t HBUF_OFF  = FLAGS_OFF + 256 * 64;
  const size_t WIBF_OFF  = HBUF_OFF + (size_t)2 * NBNH * 2;
  const size_t XBF_OFF   = WIBF_OFF + (size_t)4096 * 1024 * 2;
  const size_t XW_OFF    = XBF_OFF + (size_t)NB * NT * NI * 2;
  const size_t WS_HOIST  = XW_OFF + (size_t)NB * NT * 4096 * 2;
  const size_t WS_PATHA  = XW_OFF;

  unsigned* cnt = (unsigned*)d_ws;
  unsigned* epoch = (ws_size >= HBUF_OFF)
      ? (unsigned*)((char*)d_ws + EPOCH_OFF) : nullptr;
  unsigned* flags = (ws_size >= HBUF_OFF)
      ? (unsigned*)((char*)d_ws + FLAGS_OFF) : nullptr;
  const bool hbuf_in_ws = ws_size >= WIBF_OFF;

  unsigned short* hbuf = hbuf_in_ws
      ? (unsigned short*)((char*)d_ws + HBUF_OFF)
      : (unsigned short*)(out + (size_t)NB * NT * NH);
  unsigned short* wibf = (unsigned short*)((char*)d_ws + WIBF_OFF);
  unsigned short* xbf  = (unsigned short*)((char*)d_ws + XBF_OFF);
  unsigned short* xw   = (unsigned short*)((char*)d_ws + XW_OFF);

  reset_bar<<<dim3(1), dim3(256), 0, stream>>>(cnt, flags, epoch);

  if (ws_size >= WS_HOIST) {
    int n4x = (NB * NT * NI) / 4;
    cvt_bf16_lin<<<dim3(n4x / 256), dim3(256), 0, stream>>>(x, xbf, n4x);
    int n4w = (4096 * 1024) / 4;
    cvt_bf16_lin<<<dim3(n4w / 256), dim3(256), 0, stream>>>(Wi, wibf, n4w);
    gemm_xw2<<<dim3(8192), dim3(256), 0, stream>>>(xbf, wibf, xw);
    lstm_hoist<<<dim3(HWG), dim3(512), 0, stream>>>(xw, Wh, out, hbuf,
                                                    cnt, flags, epoch);
  } else if (ws_size >= WS_PATHA) {
    int n4x = (NB * NT * NI) / 4;
    cvt_bf16_lin<<<dim3(n4x / 256), dim3(256), 0, stream>>>(x, xbf, n4x);
    lstm_seq<true><<<dim3(256), dim3(256), 0, stream>>>(
        nullptr, xbf, Wi, Wh, out, hbuf, cnt, flags, epoch);
  } else {
    lstm_seq<false><<<dim3(256), dim3(256), 0, stream>>>(
        x, nullptr, Wi, Wh, out, hbuf, cnt, flags, epoch);
  }
}

// Round 15
// 3614.334 us; speedup vs baseline: 1.8661x; 1.0377x over previous
//
#include <hip/hip_runtime.h>

typedef __attribute__((ext_vector_type(8))) short sv8;       // 8 x bf16
typedef __attribute__((ext_vector_type(4))) float fv4;       // MFMA acc
typedef __attribute__((ext_vector_type(4))) unsigned int uv4;// 16B payload

#define NB 64
#define NT 512
#define NI 1024
#define NH 1024
#define NBNH (NB * NH)
#define HWG 128            // lstm_hoist workgroups (8 h-cols each)

__device__ __forceinline__ unsigned short f2bf(float f) {
  union { float f; unsigned u; } v; v.f = f;
  unsigned r = v.u + 0x7fffu + ((v.u >> 16) & 1u);  // RNE
  return (unsigned short)(r >> 16);
}
__device__ __forceinline__ float bf2f(unsigned short h) {
  union { unsigned u; float f; } v;
  v.u = ((unsigned)h) << 16;
  return v.f;
}
__device__ __forceinline__ float sigf(float x) {
  return 1.0f / (1.0f + __expf(-x));
}
__device__ __forceinline__ float tanhfast(float x) {
  return 2.0f * sigf(2.0f * x) - 1.0f;
}
__device__ __forceinline__ sv8 ldcvt8(const float* p) {
  float4 a = *reinterpret_cast<const float4*>(p);
  float4 b = *reinterpret_cast<const float4*>(p + 4);
  union { sv8 v; unsigned short u[8]; } r;
  r.u[0] = f2bf(a.x); r.u[1] = f2bf(a.y); r.u[2] = f2bf(a.z); r.u[3] = f2bf(a.w);
  r.u[4] = f2bf(b.x); r.u[5] = f2bf(b.y); r.u[6] = f2bf(b.z); r.u[7] = f2bf(b.w);
  return r.v;
}

// MALL-coherent accessors (agent-scope RELAXED -> sc0 sc1, no cache maint.)
__device__ __forceinline__ unsigned long long ld8_coh(const unsigned short* p) {
  return __hip_atomic_load((const unsigned long long*)p,
                           __ATOMIC_RELAXED, __HIP_MEMORY_SCOPE_AGENT);
}
__device__ __forceinline__ void st2_coh(unsigned short* p, unsigned short v) {
  __hip_atomic_store(p, v, __ATOMIC_RELAXED, __HIP_MEMORY_SCOPE_AGENT);
}
__device__ __forceinline__ void st8_coh(unsigned long long* p, unsigned long long v) {
  __hip_atomic_store(p, v, __ATOMIC_RELAXED, __HIP_MEMORY_SCOPE_AGENT);
}
__device__ __forceinline__ unsigned ld4_coh(const unsigned* p) {
  return __hip_atomic_load(p, __ATOMIC_RELAXED, __HIP_MEMORY_SCOPE_AGENT);
}
__device__ __forceinline__ void st4_coh(unsigned* p, unsigned v) {
  __hip_atomic_store(p, v, __ATOMIC_RELAXED, __HIP_MEMORY_SCOPE_AGENT);
}

union hfrag { sv8 v; unsigned long long q[2]; };

// 16 x 16B coherent loads (64B apart), single waitcnt (proven round 12).
__device__ __forceinline__ void ld_h_block(const unsigned short* hr, uv4 hh[16]) {
  asm volatile(
      "global_load_dwordx4 %0, %16, off sc0 sc1\n\t"
      "global_load_dwordx4 %1, %16, off offset:64 sc0 sc1\n\t"
      "global_load_dwordx4 %2, %16, off offset:128 sc0 sc1\n\t"
      "global_load_dwordx4 %3, %16, off offset:192 sc0 sc1\n\t"
      "global_load_dwordx4 %4, %16, off offset:256 sc0 sc1\n\t"
      "global_load_dwordx4 %5, %16, off offset:320 sc0 sc1\n\t"
      "global_load_dwordx4 %6, %16, off offset:384 sc0 sc1\n\t"
      "global_load_dwordx4 %7, %16, off offset:448 sc0 sc1\n\t"
      "global_load_dwordx4 %8, %16, off offset:512 sc0 sc1\n\t"
      "global_load_dwordx4 %9, %16, off offset:576 sc0 sc1\n\t"
      "global_load_dwordx4 %10, %16, off offset:640 sc0 sc1\n\t"
      "global_load_dwordx4 %11, %16, off offset:704 sc0 sc1\n\t"
      "global_load_dwordx4 %12, %16, off offset:768 sc0 sc1\n\t"
      "global_load_dwordx4 %13, %16, off offset:832 sc0 sc1\n\t"
      "global_load_dwordx4 %14, %16, off offset:896 sc0 sc1\n\t"
      "global_load_dwordx4 %15, %16, off offset:960 sc0 sc1\n\t"
      "s_waitcnt vmcnt(0)"
      : "=&v"(hh[0]), "=&v"(hh[1]), "=&v"(hh[2]), "=&v"(hh[3]),
        "=&v"(hh[4]), "=&v"(hh[5]), "=&v"(hh[6]), "=&v"(hh[7]),
        "=&v"(hh[8]), "=&v"(hh[9]), "=&v"(hh[10]), "=&v"(hh[11]),
        "=&v"(hh[12]), "=&v"(hh[13]), "=&v"(hh[14]), "=&v"(hh[15])
      : "v"(hr)
      : "memory");
}

__global__ void reset_bar(unsigned* cnt, unsigned* flags, unsigned* epoch) {
  if (threadIdx.x == 0) { st4_coh(cnt, 0u); if (epoch) st4_coh(epoch, 0u); }
  if (flags) st4_coh(flags + threadIdx.x * 16, 0u);
}

__global__ void cvt_bf16_lin(const float* __restrict__ in,
                             unsigned short* __restrict__ out, int n4) {
  int i = blockIdx.x * blockDim.x + threadIdx.x;
  if (i >= n4) return;
  float4 v = reinterpret_cast<const float4*>(in)[i];
  ushort4 o;
  o.x = f2bf(v.x); o.y = f2bf(v.y); o.z = f2bf(v.z); o.w = f2bf(v.w);
  reinterpret_cast<ushort4*>(out)[i] = o;
}

// ---- two-level barrier (round-12 form) kept for the fallback kernel ----
template <int NWGS>
__device__ __forceinline__ void bar_arrive(unsigned* cnt, unsigned* flags,
                                           unsigned k) {
  if (flags) {
    if (threadIdx.x == 0) st4_coh(flags + blockIdx.x * 16, k);
  } else {
    if (threadIdx.x == 0)
      __hip_atomic_fetch_add(cnt, 1u, __ATOMIC_RELAXED, __HIP_MEMORY_SCOPE_AGENT);
  }
}
template <int NWGS>
__device__ __forceinline__ void bar_wait(unsigned* cnt, unsigned* flags,
                                         unsigned* epoch, unsigned k) {
  if (flags) {
    if (blockIdx.x == 0) {
      if (threadIdx.x < 64) {
        const unsigned* f = flags + threadIdx.x * 16;
        for (;;) {
          bool ok = true;
#pragma unroll
          for (int q = 0; q < NWGS / 64; ++q)
            ok &= (ld4_coh(f + q * 64 * 16) >= k);
          if (__all(ok)) break;
          __builtin_amdgcn_s_sleep(1);
        }
        if (threadIdx.x == 0) st4_coh(epoch, k);
      }
    } else {
      if (threadIdx.x == 0) {
        while (ld4_coh(epoch) < k) __builtin_amdgcn_s_sleep(2);
      }
    }
  } else {
    if (threadIdx.x == 0) {
      const unsigned target = k * NWGS;
      while (ld4_coh(cnt) < target) __builtin_amdgcn_s_sleep(4);
    }
  }
  __syncthreads();
}

// ---- LDS-staged GEMM (validated round 13): xw = x @ Wi^T, bf16 out ----
__global__ void __launch_bounds__(256) gemm_xw2(
    const unsigned short* __restrict__ xbf,
    const unsigned short* __restrict__ wibf,
    unsigned short* __restrict__ xw)
{
  const int sg   = blockIdx.x & 255;
  const int ng   = blockIdx.x >> 8;
  const int s0   = sg << 7;
  const int n0   = ng << 7;
  const int tid  = threadIdx.x;
  const int lane = tid & 63;
  const int wv   = tid >> 6;
  const int wm   = wv >> 1;
  const int wn   = wv & 1;
  const int c    = lane & 15;
  const int ko   = (lane >> 4) << 3;

  __shared__ unsigned short As[128][72];
  __shared__ unsigned short Bs[128][72];

  const int lrow  = tid >> 1;
  const int lhalf = (tid & 1) << 5;

  fv4 acc[4][4];
#pragma unroll
  for (int i = 0; i < 4; ++i)
#pragma unroll
    for (int j = 0; j < 4; ++j) acc[i][j] = fv4{0.f, 0.f, 0.f, 0.f};

  const unsigned short* ag = xbf  + (size_t)(s0 + lrow) * NI + lhalf;
  const unsigned short* bg = wibf + (size_t)(n0 + lrow) * NI + lhalf;

  for (int k0 = 0; k0 < NI; k0 += 64) {
#pragma unroll
    for (int q = 0; q < 4; ++q) {
      *reinterpret_cast<sv8*>(&As[lrow][lhalf + q * 8]) =
          *reinterpret_cast<const sv8*>(ag + k0 + q * 8);
      *reinterpret_cast<sv8*>(&Bs[lrow][lhalf + q * 8]) =
          *reinterpret_cast<const sv8*>(bg + k0 + q * 8);
    }
    __syncthreads();

#pragma unroll
    for (int kk = 0; kk < 64; kk += 32) {
      sv8 aF[4], bF[4];
#pragma unroll
      for (int i = 0; i < 4; ++i)
        aF[i] = *reinterpret_cast<const sv8*>(&As[(wm << 6) + (i << 4) + c][kk + ko]);
#pragma unroll
      for (int j = 0; j < 4; ++j)
        bF[j] = *reinterpret_cast<const sv8*>(&Bs[(wn << 6) + (j << 4) + c][kk + ko]);
#pragma unroll
      for (int i = 0; i < 4; ++i)
#pragma unroll
        for (int j = 0; j < 4; ++j)
          acc[i][j] = __builtin_amdgcn_mfma_f32_16x16x32_bf16(
              aF[i], bF[j], acc[i][j], 0, 0, 0);
    }
    __syncthreads();
  }

#pragma unroll
  for (int i = 0; i < 4; ++i)
#pragma unroll
    for (int j = 0; j < 4; ++j) {
      int row = s0 + (wm << 6) + (i << 4) + ((lane >> 4) << 2);
      int col = n0 + (wn << 6) + (j << 4) + c;
#pragma unroll
      for (int r = 0; r < 4; ++r)
        xw[(size_t)(row + r) * 4096 + col] = f2bf(acc[i][j][r]);
    }
}

// ---- hoisted serial loop: preact = xw[s] + h_t @ Wh^T ----
// ROUND-15: one-hop barrier. arrive = flag store (after syncthreads drain).
// wait = wave 0 polls all 128 flags directly (2/lane); on detect it writes a
// monotone LDS word; waves 1-7 spin on LDS (zero fabric traffic). Removes the
// epoch publish hop + consumer MALL poll + consumer __syncthreads from the
// per-step critical path (round-14 post-mortem: ~1.5-2 us of pure latency).
__global__ void __launch_bounds__(512, 2) lstm_hoist(
    const unsigned short* __restrict__ xw,
    const float* __restrict__ Wh,
    float* out,
    unsigned short* hbuf,
    unsigned* cnt, unsigned* flags, unsigned* epoch)
{
  const int w    = ((blockIdx.x & 7) << 4) | (blockIdx.x >> 3);  // XCD swizzle
  const int tid  = threadIdx.x;
  const int lane = tid & 63;
  const int wv   = tid >> 6;
  const int half = wv >> 2;
  const int wq   = wv & 3;
  const int c    = lane & 15;
  const int ko   = (lane >> 4) << 3;
  (void)cnt; (void)epoch;

  __shared__ float pre2[2][64][33];
  __shared__ unsigned lds_sig;        // monotone barrier epoch, WG-local

  if (tid == 0) lds_sig = 0;

  // weight fragments: 2 col-tiles x 16 k-steps = 128 VGPR/lane
  sv8 bWh[2][16];
#pragma unroll
  for (int ct = 0; ct < 2; ++ct) {
    int j = (ct << 4) + c;
    int n = ((j >> 3) << 10) + (w << 3) + (j & 7);
    const float* wh = Wh + (size_t)n * NH + half * 512 + ko;
#pragma unroll
    for (int kk = 0; kk < 16; ++kk) {
      union { sv8 v; unsigned short u[8]; } ph;
#pragma unroll
      for (int jj = 0; jj < 8; ++jj) ph.u[jj] = f2bf(wh[kk * 32 + jj]);
      bWh[ct][kk] = ph.v;
    }
  }

  // zero h_0 (buffer 0): 128 WGs x 512 thr == NBNH exactly
  st2_coh(hbuf + (w << 9) + tid, 0);

  unsigned bar = 1;
  __syncthreads();                    // drains zero-stores; lds_sig visible
  if (tid == 0) st4_coh(flags + blockIdx.x * 16, bar);

  // one-hop wait: wave0 polls flags; others spin on LDS
  auto hwait = [&](unsigned k) {
    if (wv == 0) {
      const unsigned* f0 = flags + lane * 16;
      const unsigned* f1 = flags + (lane + 64) * 16;
      for (;;) {
        bool ok = (ld4_coh(f0) >= k) & (ld4_coh(f1) >= k);
        if (__all(ok)) break;
        __builtin_amdgcn_s_sleep(1);
      }
      if (lane == 0)
        __hip_atomic_store(&lds_sig, k, __ATOMIC_RELAXED,
                           __HIP_MEMORY_SCOPE_WORKGROUP);
    } else {
      while (__hip_atomic_load(&lds_sig, __ATOMIC_RELAXED,
                               __HIP_MEMORY_SCOPE_WORKGROUP) < k)
        __builtin_amdgcn_s_sleep(1);
    }
  };
  hwait(bar);

  const int b    = tid >> 3;          // gate phase: all 512 threads
  const int d    = tid & 7;
  const int jcol = (w << 3) + d;
  const int arow = (wq << 4) + c;

  float cstate = 0.0f, hlast = 0.0f;

  unsigned short xwc[4] = {0, 0, 0, 0};
  {
    const unsigned short* xwp = xw + ((size_t)b * NT + 0) * 4096 + jcol;
#pragma unroll
    for (int g = 0; g < 4; ++g) xwc[g] = xwp[g * 1024];
  }

  for (int t = 0; t < NT; ++t) {
    const unsigned short* hr =
        hbuf + (t & 1) * NBNH + arow * NH + half * 512 + ko;

    uv4 hh[16];
    ld_h_block(hr, hh);

    fv4 a0 = {0.f, 0.f, 0.f, 0.f}, a1 = a0;
#pragma unroll
    for (int kk = 0; kk < 16; ++kk) {
      union { uv4 u; sv8 s; } ca;
      ca.u = hh[kk];
      a0 = __builtin_amdgcn_mfma_f32_16x16x32_bf16(ca.s, bWh[0][kk], a0, 0, 0, 0);
      a1 = __builtin_amdgcn_mfma_f32_16x16x32_bf16(ca.s, bWh[1][kk], a1, 0, 0, 0);
    }

    // D layout: row = (lane>>4)*4 + r, col = lane&15
    {
      int prow = (wq << 4) + ((lane >> 4) << 2);
#pragma unroll
      for (int r = 0; r < 4; ++r) {
        pre2[half][prow + r][c]      = a0[r];
        pre2[half][prow + r][16 + c] = a1[r];
      }
    }
    __syncthreads();

    // gates: thread (b,d) reads WG-local col j = g*8 + d
    float p0 = pre2[0][b][d]      + pre2[1][b][d]      + bf2f(xwc[0]);
    float p1 = pre2[0][b][8 + d]  + pre2[1][b][8 + d]  + bf2f(xwc[1]);
    float p2 = pre2[0][b][16 + d] + pre2[1][b][16 + d] + bf2f(xwc[2]);
    float p3 = pre2[0][b][24 + d] + pre2[1][b][24 + d] + bf2f(xwc[3]);
    float it = sigf(sigf(p0));
    float ft = sigf(sigf(p1));
    float ot = sigf(sigf(p2));
    float gt = tanhfast(p3);
    cstate = ft * cstate + it * gt;
    float hv = ot * tanhfast(cstate);
    hlast = hv;

    // pack 4 neighbors' bf16 h into one 8B coherent store
    {
      int hbi = (int)f2bf(hv);
      int h1 = __shfl_down(hbi, 1);
      int h2 = __shfl_down(hbi, 2);
      int h3 = __shfl_down(hbi, 3);
      if ((d & 3) == 0) {
        unsigned long long pk =
            (unsigned long long)(unsigned short)hbi |
            ((unsigned long long)(unsigned short)h1 << 16) |
            ((unsigned long long)(unsigned short)h2 << 32) |
            ((unsigned long long)(unsigned short)h3 << 48);
        st8_coh((unsigned long long*)(hbuf + ((t & 1) ^ 1) * NBNH +
                                      b * NH + (w << 3) + (d & 4)), pk);
      }
    }
    __syncthreads();                 // drains all waves' h stores (vmcnt 0)
    ++bar;
    if (tid == 0) st4_coh(flags + blockIdx.x * 16, bar);   // arrive
    // hidden under the flag-propagation / spin window:
    out[(((size_t)b * NT + t) << 10) + jcol] = hv;
    if (t + 1 < NT) {
      const unsigned short* xwp = xw + ((size_t)b * NT + t + 1) * 4096 + jcol;
#pragma unroll
      for (int g = 0; g < 4; ++g) xwc[g] = xwp[g * 1024];
    }
    hwait(bar);                      // one-hop wait (no syncthreads)
  }

  out[(size_t)NB * NT * NH + b * NH + jcol]           = hlast;
  out[(size_t)NB * NT * NH + NB * NH + b * NH + jcol] = cstate;
}

// ================= fallback (round-8 structure, validated) =================
template <bool XBF>
__global__ void __launch_bounds__(256, 1) lstm_seq(
    const float* __restrict__ xf, const unsigned short* __restrict__ xb,
    const float* __restrict__ Wi, const float* __restrict__ Wh,
    float* out, unsigned short* hbuf, unsigned* cnt, unsigned* flags,
    unsigned* epoch)
{
  const int w    = blockIdx.x;
  const int tid  = threadIdx.x;
  const int lane = tid & 63;
  const int wv   = tid >> 6;
  const int c    = lane & 15;
  const int ko   = (lane >> 4) << 3;
  const int n    = (c >> 2) * NH + (w << 2) + (c & 3);

  __shared__ float pre[64][17];

  sv8 bWi[32], bWh[32];
  {
    const float* wi = Wi + (size_t)n * NI + ko;
    const float* wh = Wh + (size_t)n * NH + ko;
#pragma unroll
    for (int kk = 0; kk < 32; ++kk) {
      union { sv8 v; unsigned short u[8]; } pi, ph;
#pragma unroll
      for (int j = 0; j < 8; ++j) {
        pi.u[j] = f2bf(wi[kk * 32 + j]);
        ph.u[j] = f2bf(wh[kk * 32 + j]);
      }
      bWi[kk] = pi.v;
      bWh[kk] = ph.v;
    }
  }

  st2_coh(hbuf + (w << 8) + tid, 0);

  unsigned bar = 1;
  __syncthreads();
  bar_arrive<256>(cnt, flags, bar);
  bar_wait<256>(cnt, flags, epoch, bar);

  const int b    = tid >> 2;
  const int d    = tid & 3;
  const int jcol = (w << 2) + d;
  const int arow = (wv << 4) + c;

  float cstate = 0.0f, hlast = 0.0f;

  for (int t = 0; t < NT; ++t) {
    const unsigned short* hr = hbuf + (t & 1) * NBNH + arow * NH + ko;
    const unsigned short* xr =
        XBF ? (xb + ((size_t)arow * NT + t) * NI + ko) : nullptr;
    const float* xrf =
        XBF ? nullptr : (xf + ((size_t)arow * NT + t) * NI + ko);

    fv4 a0 = {0.f, 0.f, 0.f, 0.f}, a1 = a0, a2 = a0, a3 = a0;
#pragma unroll
    for (int kk = 0; kk < 32; kk += 2) {
      sv8 ax0, ax1;
      if constexpr (XBF) {
        ax0 = *reinterpret_cast<const sv8*>(xr + kk * 32);
        ax1 = *reinterpret_cast<const sv8*>(xr + (kk + 1) * 32);
      } else {
        ax0 = ldcvt8(xrf + kk * 32);
        ax1 = ldcvt8(xrf + (kk + 1) * 32);
      }
      hfrag h0, h1;
      h0.q[0] = ld8_coh(hr + kk * 32);
      h0.q[1] = ld8_coh(hr + kk * 32 + 4);
      h1.q[0] = ld8_coh(hr + (kk + 1) * 32);
      h1.q[1] = ld8_coh(hr + (kk + 1) * 32 + 4);
      a0 = __builtin_amdgcn_mfma_f32_16x16x32_bf16(ax0,  bWi[kk],     a0, 0, 0, 0);
      a1 = __builtin_amdgcn_mfma_f32_16x16x32_bf16(h0.v, bWh[kk],     a1, 0, 0, 0);
      a2 = __builtin_amdgcn_mfma_f32_16x16x32_bf16(ax1,  bWi[kk + 1], a2, 0, 0, 0);
      a3 = __builtin_amdgcn_mfma_f32_16x16x32_bf16(h1.v, bWh[kk + 1], a3, 0, 0, 0);
    }
    fv4 acc = (a0 + a2) + (a1 + a3);

    {
      int prow = (wv << 4) + ((lane >> 4) << 2);
#pragma unroll
      for (int r = 0; r < 4; ++r) pre[prow + r][c] = acc[r];
    }
    __syncthreads();

    float p0 = pre[b][d];
    float p1 = pre[b][4 + d];
    float p2 = pre[b][8 + d];
    float p3 = pre[b][12 + d];
    float it = sigf(sigf(p0));
    float ft = sigf(sigf(p1));
    float ot = sigf(sigf(p2));
    float gt = tanhfast(p3);
    cstate = ft * cstate + it * gt;
    float hv = ot * tanhfast(cstate);
    hlast = hv;

    st2_coh(hbuf + ((t & 1) ^ 1) * NBNH + b * NH + jcol, f2bf(hv));
    __syncthreads();
    ++bar;
    bar_arrive<256>(cnt, flags, bar);
    out[(((size_t)b * NT + t) << 10) + jcol] = hv;
    bar_wait<256>(cnt, flags, epoch, bar);
  }

  out[(size_t)NB * NT * NH + b * NH + jcol]           = hlast;
  out[(size_t)NB * NT * NH + NB * NH + b * NH + jcol] = cstate;
}

extern "C" void kernel_launch(void* const* d_in, const int* in_sizes, int n_in,
                              void* d_out, int out_size, void* d_ws, size_t ws_size,
                              hipStream_t stream) {
  (void)in_sizes; (void)n_in; (void)out_size;
  const float* x  = (const float*)d_in[0];
  const float* Wi = (const float*)d_in[1];
  const float* Wh = (const float*)d_in[2];
  float* out = (float*)d_out;

  const size_t EPOCH_OFF = 64;
  const size_t FLAGS_OFF = 128;
  const size_t HBUF_OFF  = FLAGS_OFF + 256 * 64;
  const size_t WIBF_OFF  = HBUF_OFF + (size_t)2 * NBNH * 2;
  const size_t XBF_OFF   = WIBF_OFF + (size_t)4096 * 1024 * 2;
  const size_t XW_OFF    = XBF_OFF + (size_t)NB * NT * NI * 2;
  const size_t WS_HOIST  = XW_OFF + (size_t)NB * NT * 4096 * 2;
  const size_t WS_PATHA  = XW_OFF;

  unsigned* cnt = (unsigned*)d_ws;
  unsigned* epoch = (ws_size >= HBUF_OFF)
      ? (unsigned*)((char*)d_ws + EPOCH_OFF) : nullptr;
  unsigned* flags = (ws_size >= HBUF_OFF)
      ? (unsigned*)((char*)d_ws + FLAGS_OFF) : nullptr;
  const bool hbuf_in_ws = ws_size >= WIBF_OFF;

  unsigned short* hbuf = hbuf_in_ws
      ? (unsigned short*)((char*)d_ws + HBUF_OFF)
      : (unsigned short*)(out + (size_t)NB * NT * NH);
  unsigned short* wibf = (unsigned short*)((char*)d_ws + WIBF_OFF);
  unsigned short* xbf  = (unsigned short*)((char*)d_ws + XBF_OFF);
  unsigned short* xw   = (unsigned short*)((char*)d_ws + XW_OFF);

  reset_bar<<<dim3(1), dim3(256), 0, stream>>>(cnt, flags, epoch);

  if (ws_size >= WS_HOIST) {
    int n4x = (NB * NT * NI) / 4;
    cvt_bf16_lin<<<dim3(n4x / 256), dim3(256), 0, stream>>>(x, xbf, n4x);
    int n4w = (4096 * 1024) / 4;
    cvt_bf16_lin<<<dim3(n4w / 256), dim3(256), 0, stream>>>(Wi, wibf, n4w);
    gemm_xw2<<<dim3(8192), dim3(256), 0, stream>>>(xbf, wibf, xw);
    lstm_hoist<<<dim3(HWG), dim3(512), 0, stream>>>(xw, Wh, out, hbuf,
                                                    cnt, flags, epoch);
  } else if (ws_size >= WS_PATHA) {
    int n4x = (NB * NT * NI) / 4;
    cvt_bf16_lin<<<dim3(n4x / 256), dim3(256), 0, stream>>>(x, xbf, n4x);
    lstm_seq<true><<<dim3(256), dim3(256), 0, stream>>>(
        nullptr, xbf, Wi, Wh, out, hbuf, cnt, flags, epoch);
  } else {
    lstm_seq<false><<<dim3(256), dim3(256), 0, stream>>>(
        x, nullptr, Wi, Wh, out, hbuf, cnt, flags, epoch);
  }
}